// Round 5
// baseline (62.853 us; speedup 1.0000x reference)
//
#include <hip/hip_runtime.h>
#include <math.h>

#define HH 4
#define DD 64
#define BS 32
#define SSEL 4
#define STRIDE (HH * DD)
#define PLANES 16   // max causal key-blocks per query-block (seqlen <= 512 here)

__device__ __forceinline__ float silu_f(float x) {
    return x / (1.0f + __expf(-x));
}

// ---------------------------------------------------------------------------
// Kernel 1: block means of K and V. (unchanged, verified)
// kc[((cbase_b + blk)*HH + h)*DD + d]
__global__ __launch_bounds__(256) void nsa_compress(
        const float* __restrict__ kin, const float* __restrict__ vin,
        const int* __restrict__ offs, int B, int nbcap,
        float* __restrict__ kc, float* __restrict__ vc) {
    int wid  = (blockIdx.x * blockDim.x + threadIdx.x) >> 6;
    int lane = threadIdx.x & 63;
    if (wid >= B * nbcap * HH * 2) return;
    int kind = wid & 1;
    int rest = wid >> 1;
    int h    = rest % HH;
    int blk  = (rest / HH) % nbcap;
    int b    = rest / (HH * nbcap);
    int off  = offs[b];
    int n    = offs[b + 1] - off;
    int ncmp = (n + BS - 1) / BS;
    if (blk >= ncmp) return;
    int cbase = 0;
    for (int i = 0; i < b; ++i) cbase += (offs[i + 1] - offs[i] + BS - 1) / BS;

    int rg = lane >> 4, d16 = lane & 15;
    const float* src = kind ? vin : kin;
    const float4* sp = (const float4*)(src + (size_t)(off + blk * BS) * STRIDE + h * DD + d16 * 4);
    int rmax = min(BS, n - blk * BS);
    float4 acc = {0.f, 0.f, 0.f, 0.f};
    #pragma unroll
    for (int i = 0; i < 8; ++i) {
        int row = rg * 8 + i;
        if (row < rmax) {
            float4 x = sp[(size_t)row * (STRIDE / 4)];
            acc.x += x.x; acc.y += x.y; acc.z += x.z; acc.w += x.w;
        }
    }
    #pragma unroll
    for (int m = 16; m <= 32; m <<= 1) {
        acc.x += __shfl_xor(acc.x, m, 64);
        acc.y += __shfl_xor(acc.y, m, 64);
        acc.z += __shfl_xor(acc.z, m, 64);
        acc.w += __shfl_xor(acc.w, m, 64);
    }
    if (rg == 0) {
        float4 r;
        r.x = acc.x * (1.f / BS); r.y = acc.y * (1.f / BS);
        r.z = acc.z * (1.f / BS); r.w = acc.w * (1.f / BS);
        float* dst = (kind ? vc : kc) + ((size_t)(cbase + blk) * HH + h) * DD + d16 * 4;
        *(float4*)dst = r;
    }
}

// ---------------------------------------------------------------------------
// Kernel 2: one wave per (t,h): cmp attention + top-4 selection mask.
// Requires nb_c <= 16 (seqlen <= 512).
__global__ __launch_bounds__(256) void nsa_cmp_sel(
        const float* __restrict__ q, const float* __restrict__ gc,
        const int* __restrict__ offs, const float* __restrict__ kc,
        const float* __restrict__ vc, int B, int T,
        float* __restrict__ out, unsigned int* __restrict__ selws) {
    __shared__ float lds_q[4][DD];
    int lane = threadIdx.x & 63;
    int wvb  = threadIdx.x >> 6;
    int wid  = blockIdx.x * 4 + wvb;
    if (wid >= T * HH) return;
    int h = wid % HH;
    int t = wid / HH;

    int b = 0;
    while (t >= offs[b + 1]) ++b;
    int off = offs[b];
    int lq  = t - off;
    int qblk = lq >> 5;
    int cbase = 0;
    for (int i = 0; i < b; ++i) cbase += (offs[i + 1] - offs[i] + BS - 1) / BS;
    int nb_c = qblk + 1;                      // <= 16
    const float scale = 0.125f;

    lds_q[wvb][lane] = q[(size_t)t * STRIDE + h * DD + lane] * scale;
    const float4* sq4 = (const float4*)lds_q[wvb];

    int blkq = lane >> 2;                     // block 0..15
    int dq   = lane & 3;                      // d-quarter
    bool valid = blkq < nb_c;
    int  cblk  = cbase + (valid ? blkq : 0);
    const float4* kcp = (const float4*)(kc + ((size_t)cblk * HH + h) * DD + dq * 16);
    float s = 0.f;
    #pragma unroll
    for (int j = 0; j < 4; ++j) {
        float4 kk = kcp[j];
        float4 qq = sq4[dq * 4 + j];
        s += kk.x * qq.x + kk.y * qq.y + kk.z * qq.z + kk.w * qq.w;
    }
    s += __shfl_xor(s, 1, 64);
    s += __shfl_xor(s, 2, 64);

    float s_m = valid ? s : -INFINITY;
    float p   = valid ? silu_f(s) : 0.f;

    // rank of own block among the 16 group scores (strict >, lower idx wins)
    int rank = 0;
    #pragma unroll
    for (int j = 0; j < 16; ++j) {
        float scj = __shfl(s_m, j * 4, 64);
        rank += (scj > s_m) || (scj == s_m && j < blkq);
    }
    int bit = (valid && rank < SSEL) ? 1 : 0;

    // assemble 16-bit mask: lane L<16 fetches bit of group L
    int bg = __shfl(bit, (lane & 15) * 4, 64);
    unsigned long long bal = __ballot(lane < 16 && bg);
    unsigned int m16 = (unsigned int)(bal & 0xFFFFull);

    int qb_global = cbase + qblk;
    if (lane == 0)
        selws[((size_t)qb_global * HH + h) * 32 + (lq & 31)] = m16;

    // cmp PV: lane = d
    float o = 0.f;
    const float* vcb = vc + ((size_t)cbase * HH + h) * DD + lane;
    for (int j = 0; j < nb_c; ++j) {
        float pj = __shfl(p, j * 4, 64);
        o += pj * vcb[(size_t)j * STRIDE];
    }
    out[(size_t)t * STRIDE + h * DD + lane] = o * gc[t * HH + h];
}

// ---------------------------------------------------------------------------
// Kernel 3: selection attention. One wave per (query-block, head, key-block).
// Workgroup = (qbh, jj); wave w handles kb = jj*4 + w (+16 per extra iter).
// Writes partial[qbh*PLANES + kb][32 q][64 d] to ws.
__global__ __launch_bounds__(256) void nsa_slc(
        const float* __restrict__ q, const float* __restrict__ k,
        const float* __restrict__ v, const int* __restrict__ offs,
        const unsigned int* __restrict__ selws, int B, int T,
        float* __restrict__ partial) {
    __shared__ float Qs[32][DD];            // 8 KB, scaled q
    __shared__ float Vs[4][32][DD];         // 32 KB, chunk-XOR swizzled
    __shared__ float Ps[4][32 * 33];        // 16.9 KB, pad-33
    __shared__ unsigned int Ms[32];

    int wgid = blockIdx.x;
    int jj   = wgid & 3;
    int qbh  = wgid >> 2;
    int h    = qbh & (HH - 1);
    int qb   = qbh / HH;

    // map global query-block -> (batch, local block)
    int b = -1, lb = 0, cum = 0, off = 0, n = 0;
    for (int i = 0; i < B; ++i) {
        int o0 = offs[i], o1 = offs[i + 1];
        int nbi = (o1 - o0 + BS - 1) / BS;
        if (qb < cum + nbi) { b = i; lb = qb - cum; off = o0; n = o1 - o0; break; }
        cum += nbi;
    }
    if (b < 0) return;
    int t0 = off + lb * BS;
    const float scale = 0.125f;

    // cooperative stage: Q block (scaled) + selection masks
    {
        int row = threadIdx.x >> 3, c = threadIdx.x & 7;
        float4 v0 = {0.f,0.f,0.f,0.f}, v1 = v0;
        if (lb * BS + row < n) {
            const float4* qp = (const float4*)(q + (size_t)(t0 + row) * STRIDE + h * DD + c * 8);
            v0 = qp[0]; v1 = qp[1];
        }
        v0.x*=scale; v0.y*=scale; v0.z*=scale; v0.w*=scale;
        v1.x*=scale; v1.y*=scale; v1.z*=scale; v1.w*=scale;
        *(float4*)&Qs[row][c * 8]     = v0;
        *(float4*)&Qs[row][c * 8 + 4] = v1;
        if (threadIdx.x < 32)
            Ms[threadIdx.x] = (lb * BS + (int)threadIdx.x < n)
                ? selws[(size_t)qbh * 32 + threadIdx.x] : 0u;
    }
    __syncthreads();

    int w = threadIdx.x >> 6, lane = threadIdx.x & 63;

    for (int kb = jj * 4 + w; kb <= lb; kb += 16) {
        if (kb >= PLANES) break;   // harness: lb <= 15
        int r = lane & 31, half = lane >> 5;
        int kr = min(off + kb * BS + r, T - 1);

        // K row-half in registers
        const float4* kp = (const float4*)(k + (size_t)kr * STRIDE + h * DD + half * 32);
        float4 K[8];
        #pragma unroll
        for (int j = 0; j < 8; ++j) K[j] = kp[j];

        // stage V (same rows), chunk-XOR swizzle (G4: avoid stride-64 bank clash)
        const float4* vp = (const float4*)(v + (size_t)kr * STRIDE + h * DD + half * 32);
        #pragma unroll
        for (int j = 0; j < 8; ++j) {
            int cc = (half * 8 + j) ^ (r & 7);
            *((float4*)&Vs[w][r][0] + cc) = vp[j];
        }
        // zero P
        for (int i = lane; i < 32 * 33; i += 64) Ps[w][i] = 0.f;

        bool any = false;
        for (int qq = 0; qq < 32; ++qq) {
            unsigned int mq = Ms[qq];
            if (!((mq >> kb) & 1u)) continue;
            any = true;
            const float4* qrow = (const float4*)&Qs[qq][half * 32];
            float s = 0.f;
            #pragma unroll
            for (int j = 0; j < 8; ++j) {
                float4 a = qrow[j], bb = K[j];
                s += a.x * bb.x + a.y * bb.y + a.z * bb.z + a.w * bb.w;
            }
            s += __shfl_xor(s, 32, 64);
            bool vmask = (kb < lb) || (r <= qq);
            float p = vmask ? silu_f(s) : 0.f;
            if (half == 0) Ps[w][qq * 33 + r] = p;
        }

        // PV: lane = (q, d-half); acc 32 f32 in regs
        int q2 = lane & 31, dh = lane >> 5;
        float4 acc[8];
        #pragma unroll
        for (int j = 0; j < 8; ++j) acc[j] = (float4){0.f,0.f,0.f,0.f};
        if (any) {
            for (int r2 = 0; r2 < 32; ++r2) {
                float pv = Ps[w][q2 * 33 + r2];
                const float4* vrow = (const float4*)&Vs[w][r2][0];
                #pragma unroll
                for (int j = 0; j < 8; ++j) {
                    int cc = (dh * 8 + j) ^ (r2 & 7);
                    float4 vv = vrow[cc];
                    acc[j].x += pv * vv.x; acc[j].y += pv * vv.y;
                    acc[j].z += pv * vv.z; acc[j].w += pv * vv.w;
                }
            }
        }
        float4* dst = (float4*)(partial + ((size_t)qbh * PLANES + kb) * (32 * DD)
                                + q2 * DD + dh * 32);
        #pragma unroll
        for (int j = 0; j < 8; ++j) dst[j] = acc[j];
    }
}

// ---------------------------------------------------------------------------
// Kernel 4: combine partials over kb, gate with g_slc, write o_slc.
__global__ __launch_bounds__(256) void nsa_combine(
        const float* __restrict__ partial, const float* __restrict__ gs,
        const int* __restrict__ offs, int B, int T,
        float* __restrict__ out) {
    int qbh = blockIdx.x;
    int h   = qbh & (HH - 1);
    int qb  = qbh / HH;

    int b = -1, lb = 0, cum = 0, off = 0, n = 0;
    for (int i = 0; i < B; ++i) {
        int o0 = offs[i], o1 = offs[i + 1];
        int nbi = (o1 - o0 + BS - 1) / BS;
        if (qb < cum + nbi) { b = i; lb = qb - cum; off = o0; n = o1 - o0; break; }
        cum += nbi;
    }
    if (b < 0) return;

    int qq = threadIdx.x >> 3, c = threadIdx.x & 7;
    if (lb * BS + qq >= n) return;
    int t = off + lb * BS + qq;

    float4 a0 = {0.f,0.f,0.f,0.f}, a1 = a0;
    int kmax = min(lb, PLANES - 1);
    for (int kb = 0; kb <= kmax; ++kb) {
        const float4* sp = (const float4*)(partial + ((size_t)qbh * PLANES + kb) * (32 * DD)
                                           + qq * DD + c * 8);
        float4 x0 = sp[0], x1 = sp[1];
        a0.x += x0.x; a0.y += x0.y; a0.z += x0.z; a0.w += x0.w;
        a1.x += x1.x; a1.y += x1.y; a1.z += x1.z; a1.w += x1.w;
    }
    float g = gs[(size_t)t * HH + h];
    a0.x *= g; a0.y *= g; a0.z *= g; a0.w *= g;
    a1.x *= g; a1.y *= g; a1.z *= g; a1.w *= g;
    float4* op = (float4*)(out + (size_t)T * STRIDE + (size_t)t * STRIDE + h * DD + c * 8);
    op[0] = a0; op[1] = a1;
}

// ---------------------------------------------------------------------------
extern "C" void kernel_launch(void* const* d_in, const int* in_sizes, int n_in,
                              void* d_out, int out_size, void* d_ws, size_t ws_size,
                              hipStream_t stream) {
    const float* q    = (const float*)d_in[0];
    const float* k    = (const float*)d_in[1];
    const float* v    = (const float*)d_in[2];
    const float* gc   = (const float*)d_in[3];
    const float* gs   = (const float*)d_in[4];
    const int*   offs = (const int*)d_in[5];   // JAX x64-off: int32 on device

    int B = in_sizes[5] - 1;
    int T = out_size / (2 * STRIDE);
    int nbcap  = (T + BS - 1) / BS;
    int nqbcap = nbcap + B;                    // upper bound on global query-blocks

    // ws layout: kc | vc | selmask | partial
    size_t cmp_elems = (size_t)(nbcap + B) * STRIDE;
    float* kc = (float*)d_ws;
    float* vc = kc + cmp_elems;
    unsigned int* selws = (unsigned int*)(vc + cmp_elems);
    // align partial to 256B
    size_t sel_end = ((size_t)(2 * cmp_elems) * 4 + (size_t)nqbcap * HH * 32 * 4 + 255) & ~(size_t)255;
    float* partial = (float*)((char*)d_ws + sel_end);
    // partial size: nqbcap*HH*PLANES*32*64*4 ~ 28 MB (ws is ~256 MB)

    dim3 blk(256);
    int waves1 = B * nbcap * HH * 2;
    nsa_compress<<<dim3((unsigned)((waves1 * 64 + 255) / 256)), blk, 0, stream>>>(
        k, v, offs, B, nbcap, kc, vc);

    nsa_cmp_sel<<<dim3((unsigned)((T * HH + 3) / 4)), blk, 0, stream>>>(
        q, gc, offs, kc, vc, B, T, (float*)d_out, selws);

    nsa_slc<<<dim3((unsigned)(nqbcap * HH * 4)), blk, 0, stream>>>(
        q, k, v, offs, selws, B, T, partial);

    nsa_combine<<<dim3((unsigned)(nqbcap * HH)), blk, 0, stream>>>(
        partial, gs, offs, B, T, (float*)d_out);
}

// Round 6
// 28.242 us; speedup vs baseline: 2.2255x; 2.2255x over previous
//
#include <hip/hip_runtime.h>
#include <math.h>

#define HH 4
#define DD 64
#define BS 32
#define SSEL 4
#define STRIDE (HH * DD)

typedef __attribute__((ext_vector_type(8))) short bf16x8;
typedef __attribute__((ext_vector_type(4))) float f32x4;

__device__ __forceinline__ float silu_f(float x) { return x / (1.0f + __expf(-x)); }

__device__ __forceinline__ unsigned short f2bf(float f) {
    unsigned int x = __float_as_uint(f);
    return (unsigned short)((x + 0x7FFFu + ((x >> 16) & 1u)) >> 16);   // RNE
}
__device__ __forceinline__ unsigned int pk2bf(float a, float b) {
    return (unsigned int)f2bf(a) | ((unsigned int)f2bf(b) << 16);
}

// ---------------------------------------------------------------------------
// Kernel 1: block means of K and V. (verified)
__global__ __launch_bounds__(256) void nsa_compress(
        const float* __restrict__ kin, const float* __restrict__ vin,
        const int* __restrict__ offs, int B, int nbcap,
        float* __restrict__ kc, float* __restrict__ vc) {
    int wid  = (blockIdx.x * blockDim.x + threadIdx.x) >> 6;
    int lane = threadIdx.x & 63;
    if (wid >= B * nbcap * HH * 2) return;
    int kind = wid & 1;
    int rest = wid >> 1;
    int h    = rest % HH;
    int blk  = (rest / HH) % nbcap;
    int b    = rest / (HH * nbcap);
    int off  = offs[b];
    int n    = offs[b + 1] - off;
    int ncmp = (n + BS - 1) / BS;
    if (blk >= ncmp) return;
    int cbase = 0;
    for (int i = 0; i < b; ++i) cbase += (offs[i + 1] - offs[i] + BS - 1) / BS;

    int rg = lane >> 4, d16 = lane & 15;
    const float* src = kind ? vin : kin;
    const float4* sp = (const float4*)(src + (size_t)(off + blk * BS) * STRIDE + h * DD + d16 * 4);
    int rmax = min(BS, n - blk * BS);
    float4 acc = {0.f, 0.f, 0.f, 0.f};
    #pragma unroll
    for (int i = 0; i < 8; ++i) {
        int row = rg * 8 + i;
        if (row < rmax) {
            float4 x = sp[(size_t)row * (STRIDE / 4)];
            acc.x += x.x; acc.y += x.y; acc.z += x.z; acc.w += x.w;
        }
    }
    #pragma unroll
    for (int m = 16; m <= 32; m <<= 1) {
        acc.x += __shfl_xor(acc.x, m, 64);
        acc.y += __shfl_xor(acc.y, m, 64);
        acc.z += __shfl_xor(acc.z, m, 64);
        acc.w += __shfl_xor(acc.w, m, 64);
    }
    if (rg == 0) {
        float4 r;
        r.x = acc.x * (1.f / BS); r.y = acc.y * (1.f / BS);
        r.z = acc.z * (1.f / BS); r.w = acc.w * (1.f / BS);
        float* dst = (kind ? vc : kc) + ((size_t)(cbase + blk) * HH + h) * DD + d16 * 4;
        *(float4*)dst = r;
    }
}

// ---------------------------------------------------------------------------
// Kernel 2: one wave per (t,h): cmp attention (fp32 exact) + top-4 sel mask. (verified)
__global__ __launch_bounds__(256) void nsa_cmp_sel(
        const float* __restrict__ q, const float* __restrict__ gc,
        const int* __restrict__ offs, const float* __restrict__ kc,
        const float* __restrict__ vc, int B, int T,
        float* __restrict__ out, unsigned int* __restrict__ selws) {
    __shared__ float lds_q[4][DD];
    int lane = threadIdx.x & 63;
    int wvb  = threadIdx.x >> 6;
    int wid  = blockIdx.x * 4 + wvb;
    if (wid >= T * HH) return;
    int h = wid % HH;
    int t = wid / HH;

    int b = 0;
    while (t >= offs[b + 1]) ++b;
    int off = offs[b];
    int lq  = t - off;
    int qblk = lq >> 5;
    int cbase = 0;
    for (int i = 0; i < b; ++i) cbase += (offs[i + 1] - offs[i] + BS - 1) / BS;
    int nb_c = qblk + 1;                      // <= 16
    const float scale = 0.125f;

    lds_q[wvb][lane] = q[(size_t)t * STRIDE + h * DD + lane] * scale;
    const float4* sq4 = (const float4*)lds_q[wvb];

    int blkq = lane >> 2;                     // block 0..15
    int dq   = lane & 3;                      // d-quarter
    bool valid = blkq < nb_c;
    int  cblk  = cbase + (valid ? blkq : 0);
    const float4* kcp = (const float4*)(kc + ((size_t)cblk * HH + h) * DD + dq * 16);
    float s = 0.f;
    #pragma unroll
    for (int j = 0; j < 4; ++j) {
        float4 kk = kcp[j];
        float4 qq = sq4[dq * 4 + j];
        s += kk.x * qq.x + kk.y * qq.y + kk.z * qq.z + kk.w * qq.w;
    }
    s += __shfl_xor(s, 1, 64);
    s += __shfl_xor(s, 2, 64);

    float s_m = valid ? s : -INFINITY;
    float p   = valid ? silu_f(s) : 0.f;

    int rank = 0;
    #pragma unroll
    for (int j = 0; j < 16; ++j) {
        float scj = __shfl(s_m, j * 4, 64);
        rank += (scj > s_m) || (scj == s_m && j < blkq);
    }
    int bit = (valid && rank < SSEL) ? 1 : 0;

    int bg = __shfl(bit, (lane & 15) * 4, 64);
    unsigned long long bal = __ballot(lane < 16 && bg);
    unsigned int m16 = (unsigned int)(bal & 0xFFFFull);

    int qb_global = cbase + qblk;
    if (lane == 0)
        selws[((size_t)qb_global * HH + h) * 32 + (lq & 31)] = m16;

    float o = 0.f;
    const float* vcb = vc + ((size_t)cbase * HH + h) * DD + lane;
    for (int j = 0; j < nb_c; ++j) {
        float pj = __shfl(p, j * 4, 64);
        o += pj * vcb[(size_t)j * STRIDE];
    }
    out[(size_t)t * STRIDE + h * DD + lane] = o * gc[t * HH + h];
}

// ---------------------------------------------------------------------------
// Kernel 3: selection attention via MFMA bf16. One WG per (qb, h), 4 waves,
// wave w handles kb = w, w+4, ... No barriers inside the kb loop.
__global__ __launch_bounds__(256) void nsa_slc_mfma(
        const float* __restrict__ q, const float* __restrict__ k,
        const float* __restrict__ v, const float* __restrict__ gs,
        const int* __restrict__ offs, const unsigned int* __restrict__ selws,
        int B, int T, float* __restrict__ out) {
    __shared__ unsigned short Qs[32][64];        // bf16, chunk-XOR swizzled
    __shared__ unsigned short Ks[4][32][64];     // per-wave K tile
    __shared__ unsigned int   Pw[4][32][20];     // per-wave P (bf16 pairs), 80B rows
    __shared__ float          Op[4][32][67];     // per-wave O^T planes (padded)

    int qbh = blockIdx.x;
    int h   = qbh & (HH - 1);
    int qb  = qbh / HH;

    int b = -1, lb = 0, cum = 0, off = 0, n = 0;
    for (int i = 0; i < B; ++i) {
        int o0 = offs[i], o1 = offs[i + 1];
        int nbi = (o1 - o0 + BS - 1) / BS;
        if (qb < cum + nbi) { b = i; lb = qb - cum; off = o0; n = o1 - o0; break; }
        cum += nbi;
    }
    if (b < 0) return;
    int t0 = off + lb * BS;
    const float scale = 0.125f;

    // ---- stage Q (scaled -> bf16, XOR-swizzled chunks) ----
    {
        int row = threadIdx.x >> 3, dg = threadIdx.x & 7;
        const float4* qp = (const float4*)(q + (size_t)(t0 + row) * STRIDE + h * DD + dg * 8);
        float4 a = qp[0], c = qp[1];
        uint4 uu;
        uu.x = pk2bf(a.x * scale, a.y * scale);
        uu.y = pk2bf(a.z * scale, a.w * scale);
        uu.z = pk2bf(c.x * scale, c.y * scale);
        uu.w = pk2bf(c.z * scale, c.w * scale);
        *(uint4*)&Qs[row][(dg ^ (row & 7)) * 8] = uu;
    }
    __syncthreads();

    int w = threadIdx.x >> 6, lane = threadIdx.x & 63;
    int l15 = lane & 15, g = lane >> 4;

    unsigned int Msq[2];
    Msq[0] = selws[(size_t)qbh * 32 + l15];
    Msq[1] = selws[(size_t)qbh * 32 + 16 + l15];

    f32x4 oacc[4][2];
    #pragma unroll
    for (int dt = 0; dt < 4; ++dt)
        #pragma unroll
        for (int qt = 0; qt < 2; ++qt)
            oacc[dt][qt] = (f32x4){0.f, 0.f, 0.f, 0.f};

    for (int kb = w; kb <= lb; kb += 4) {
        // ---- stage this wave's K tile (bf16, XOR-swizzled) ----
        {
            int row = lane >> 1, hf = lane & 1;
            const float4* kp = (const float4*)(k + (size_t)(off + kb * BS + row) * STRIDE
                                               + h * DD + hf * 32);
            #pragma unroll
            for (int cc = 0; cc < 4; ++cc) {
                float4 x = kp[cc * 2], y = kp[cc * 2 + 1];
                uint4 uu;
                uu.x = pk2bf(x.x, x.y); uu.y = pk2bf(x.z, x.w);
                uu.z = pk2bf(y.x, y.y); uu.w = pk2bf(y.z, y.w);
                int c = hf * 4 + cc;
                *(uint4*)&Ks[w][row][(c ^ (row & 7)) * 8] = uu;
            }
        }

        // ---- QK^T (swapped): S^T[k][q], 4 tiles of 16x16, K=64 in 2 steps ----
        bf16x8 a1[2][2], b1[2][2];
        #pragma unroll
        for (int ds = 0; ds < 2; ++ds)
            #pragma unroll
            for (int tt = 0; tt < 2; ++tt) {
                a1[tt][ds] = *(bf16x8*)&Ks[w][tt * 16 + l15][((g + ds * 4) ^ (l15 & 7)) * 8];
                b1[tt][ds] = *(bf16x8*)&Qs[tt * 16 + l15][((g + ds * 4) ^ (l15 & 7)) * 8];
            }
        f32x4 s[2][2];
        #pragma unroll
        for (int kt = 0; kt < 2; ++kt)
            #pragma unroll
            for (int qt = 0; qt < 2; ++qt) {
                s[kt][qt] = (f32x4){0.f, 0.f, 0.f, 0.f};
                s[kt][qt] = __builtin_amdgcn_mfma_f32_16x16x32_bf16(a1[kt][0], b1[qt][0], s[kt][qt], 0, 0, 0);
                s[kt][qt] = __builtin_amdgcn_mfma_f32_16x16x32_bf16(a1[kt][1], b1[qt][1], s[kt][qt], 0, 0, 0);
            }

        // ---- mask + silu + pack P (bf16) into wave-private LDS ----
        #pragma unroll
        for (int kt = 0; kt < 2; ++kt)
            #pragma unroll
            for (int qt = 0; qt < 2; ++qt) {
                unsigned int mrow = Msq[qt];
                bool selb = (mrow >> kb) & 1u;
                float pv[4];
                #pragma unroll
                for (int r = 0; r < 4; ++r) {
                    int k_l = kt * 16 + g * 4 + r;
                    int q_l = qt * 16 + l15;
                    bool ok = selb && (kb < lb || k_l <= q_l);
                    pv[r] = ok ? silu_f(s[kt][qt][r]) : 0.f;
                }
                Pw[w][qt * 16 + l15][kt * 8 + g * 2 + 0] = pk2bf(pv[0], pv[1]);
                Pw[w][qt * 16 + l15][kt * 8 + g * 2 + 1] = pk2bf(pv[2], pv[3]);
            }

        // ---- B2 operands: P rows, contiguous 8 k per lane ----
        bf16x8 b2[2];
        b2[0] = *(bf16x8*)&Pw[w][l15][g * 4];
        b2[1] = *(bf16x8*)&Pw[w][16 + l15][g * 4];

        // ---- A2 operands: V^T fragments straight from global (L2-hit) ----
        const float* vg = v + (size_t)(off + kb * BS) * STRIDE + h * DD;
        bf16x8 a2[4];
        #pragma unroll
        for (int dt = 0; dt < 4; ++dt) {
            float tmp[8];
            #pragma unroll
            for (int j = 0; j < 8; ++j)
                tmp[j] = vg[(size_t)(g * 8 + j) * STRIDE + dt * 16 + l15];
            union { unsigned int u[4]; bf16x8 v8; } cu;
            cu.u[0] = pk2bf(tmp[0], tmp[1]);
            cu.u[1] = pk2bf(tmp[2], tmp[3]);
            cu.u[2] = pk2bf(tmp[4], tmp[5]);
            cu.u[3] = pk2bf(tmp[6], tmp[7]);
            a2[dt] = cu.v8;
        }

        // ---- PV: O^T += V^T @ P^T, 8 tiles, K=32 each in one MFMA ----
        #pragma unroll
        for (int dt = 0; dt < 4; ++dt)
            #pragma unroll
            for (int qt = 0; qt < 2; ++qt)
                oacc[dt][qt] = __builtin_amdgcn_mfma_f32_16x16x32_bf16(a2[dt], b2[qt], oacc[dt][qt], 0, 0, 0);
    }

    // ---- transpose-store each wave's O^T partial to its LDS plane ----
    #pragma unroll
    for (int dt = 0; dt < 4; ++dt)
        #pragma unroll
        for (int qt = 0; qt < 2; ++qt)
            #pragma unroll
            for (int r = 0; r < 4; ++r)
                Op[w][qt * 16 + l15][dt * 16 + g * 4 + r] = oacc[dt][qt][r];
    __syncthreads();

    // ---- combine 4 planes, gate, coalesced store ----
    {
        int qq = threadIdx.x >> 3, dg = threadIdx.x & 7;
        if (lb * BS + qq < n) {
            float gv = gs[(size_t)(t0 + qq) * HH + h];
            float o[8];
            #pragma unroll
            for (int i = 0; i < 8; ++i) {
                int d = dg * 8 + i;
                o[i] = (Op[0][qq][d] + Op[1][qq][d] + Op[2][qq][d] + Op[3][qq][d]) * gv;
            }
            float4* dst = (float4*)(out + (size_t)T * STRIDE + (size_t)(t0 + qq) * STRIDE
                                    + h * DD + dg * 8);
            dst[0] = (float4){o[0], o[1], o[2], o[3]};
            dst[1] = (float4){o[4], o[5], o[6], o[7]};
        }
    }
}

// ---------------------------------------------------------------------------
extern "C" void kernel_launch(void* const* d_in, const int* in_sizes, int n_in,
                              void* d_out, int out_size, void* d_ws, size_t ws_size,
                              hipStream_t stream) {
    const float* q    = (const float*)d_in[0];
    const float* k    = (const float*)d_in[1];
    const float* v    = (const float*)d_in[2];
    const float* gc   = (const float*)d_in[3];
    const float* gs   = (const float*)d_in[4];
    const int*   offs = (const int*)d_in[5];   // JAX x64-off: int32 on device

    int B = in_sizes[5] - 1;
    int T = out_size / (2 * STRIDE);
    int nbcap  = (T + BS - 1) / BS;
    int nqbcap = nbcap + B;

    size_t cmp_elems = (size_t)(nbcap + B) * STRIDE;
    float* kc = (float*)d_ws;
    float* vc = kc + cmp_elems;
    unsigned int* selws = (unsigned int*)(vc + cmp_elems);

    dim3 blk(256);
    int waves1 = B * nbcap * HH * 2;
    nsa_compress<<<dim3((unsigned)((waves1 * 64 + 255) / 256)), blk, 0, stream>>>(
        k, v, offs, B, nbcap, kc, vc);

    nsa_cmp_sel<<<dim3((unsigned)((T * HH + 3) / 4)), blk, 0, stream>>>(
        q, gc, offs, kc, vc, B, T, (float*)d_out, selws);

    nsa_slc_mfma<<<dim3((unsigned)(nqbcap * HH)), blk, 0, stream>>>(
        q, k, v, gs, offs, selws, B, T, (float*)d_out);
}

// Round 7
// 26.646 us; speedup vs baseline: 2.3588x; 1.0599x over previous
//
#include <hip/hip_runtime.h>
#include <math.h>

#define HH 4
#define DD 64
#define BS 32
#define SSEL 4
#define STRIDE (HH * DD)

typedef __attribute__((ext_vector_type(8))) short bf16x8;
typedef __attribute__((ext_vector_type(4))) float f32x4;

__device__ __forceinline__ float silu_f(float x) { return x / (1.0f + __expf(-x)); }

__device__ __forceinline__ unsigned short f2bf(float f) {
    unsigned int x = __float_as_uint(f);
    return (unsigned short)((x + 0x7FFFu + ((x >> 16) & 1u)) >> 16);   // RNE
}
__device__ __forceinline__ unsigned int pk2bf(float a, float b) {
    return (unsigned int)f2bf(a) | ((unsigned int)f2bf(b) << 16);
}

// ---------------------------------------------------------------------------
// Kernel 1: block means of K and V. (verified)
__global__ __launch_bounds__(256) void nsa_compress(
        const float* __restrict__ kin, const float* __restrict__ vin,
        const int* __restrict__ offs, int B, int nbcap,
        float* __restrict__ kc, float* __restrict__ vc) {
    int wid  = (blockIdx.x * blockDim.x + threadIdx.x) >> 6;
    int lane = threadIdx.x & 63;
    if (wid >= B * nbcap * HH * 2) return;
    int kind = wid & 1;
    int rest = wid >> 1;
    int h    = rest % HH;
    int blk  = (rest / HH) % nbcap;
    int b    = rest / (HH * nbcap);
    int off  = offs[b];
    int n    = offs[b + 1] - off;
    int ncmp = (n + BS - 1) / BS;
    if (blk >= ncmp) return;
    int cbase = 0;
    for (int i = 0; i < b; ++i) cbase += (offs[i + 1] - offs[i] + BS - 1) / BS;

    int rg = lane >> 4, d16 = lane & 15;
    const float* src = kind ? vin : kin;
    const float4* sp = (const float4*)(src + (size_t)(off + blk * BS) * STRIDE + h * DD + d16 * 4);
    int rmax = min(BS, n - blk * BS);
    float4 acc = {0.f, 0.f, 0.f, 0.f};
    #pragma unroll
    for (int i = 0; i < 8; ++i) {
        int row = rg * 8 + i;
        if (row < rmax) {
            float4 x = sp[(size_t)row * (STRIDE / 4)];
            acc.x += x.x; acc.y += x.y; acc.z += x.z; acc.w += x.w;
        }
    }
    #pragma unroll
    for (int m = 16; m <= 32; m <<= 1) {
        acc.x += __shfl_xor(acc.x, m, 64);
        acc.y += __shfl_xor(acc.y, m, 64);
        acc.z += __shfl_xor(acc.z, m, 64);
        acc.w += __shfl_xor(acc.w, m, 64);
    }
    if (rg == 0) {
        float4 r;
        r.x = acc.x * (1.f / BS); r.y = acc.y * (1.f / BS);
        r.z = acc.z * (1.f / BS); r.w = acc.w * (1.f / BS);
        float* dst = (kind ? vc : kc) + ((size_t)(cbase + blk) * HH + h) * DD + d16 * 4;
        *(float4*)dst = r;
    }
}

// ---------------------------------------------------------------------------
// Kernel 2: fused per-(query-block, head) WG: cmp scores (fp32 exact) ->
// top-4 masks -> cmp PV -> MFMA slc (round-6 verified engine).
__global__ __launch_bounds__(256) void nsa_fused(
        const float* __restrict__ q, const float* __restrict__ k,
        const float* __restrict__ v, const float* __restrict__ gc,
        const float* __restrict__ gs, const int* __restrict__ offs,
        const float* __restrict__ kc, const float* __restrict__ vc,
        int B, int T, float* __restrict__ out) {
    __shared__ float Qf[32][68];                 // f32 scaled q, padded
    __shared__ float Kc[16][68];                 // f32 kc tile, padded
    __shared__ float Vc[16][64];                 // f32 vc tile
    __shared__ float Sc[32][17];                 // cmp scores
    __shared__ float Ps[32][17];                 // silu(scores)
    __shared__ unsigned char selb[32][16];
    __shared__ unsigned int  Msk[32];
    __shared__ unsigned short Qs[32][64];        // bf16, chunk-XOR swizzled
    __shared__ unsigned short Ks[4][32][64];     // per-wave K tile
    __shared__ unsigned int   Pw[4][32][20];     // per-wave P (bf16 pairs)
    __shared__ float          Op[4][32][67];     // per-wave O^T planes

    int qbh = blockIdx.x;
    int h   = qbh & (HH - 1);
    int qb  = qbh / HH;

    int b = -1, lb = 0, cum = 0, off = 0, n = 0;
    for (int i = 0; i < B; ++i) {
        int o0 = offs[i], o1 = offs[i + 1];
        int nbi = (o1 - o0 + BS - 1) / BS;
        if (qb < cum + nbi) { b = i; lb = qb - cum; off = o0; n = o1 - o0; break; }
        cum += nbi;
    }
    if (b < 0) return;
    int cbase = cum;                 // global compressed-block base of batch b
    int t0  = off + lb * BS;
    int nbl = lb + 1;                // causal cmp blocks (uniform for all 32 q)
    const float scale = 0.125f;
    int tid = threadIdx.x;

    // ---- phase 0: stage Q (f32 + bf16 swizzled) and Kc/Vc tiles ----
    {
        int row = tid >> 3, dg = tid & 7;
        const float4* qp = (const float4*)(q + (size_t)(t0 + row) * STRIDE + h * DD + dg * 8);
        float4 a = qp[0], c = qp[1];
        a.x *= scale; a.y *= scale; a.z *= scale; a.w *= scale;
        c.x *= scale; c.y *= scale; c.z *= scale; c.w *= scale;
        *(float4*)&Qf[row][dg * 8]     = a;
        *(float4*)&Qf[row][dg * 8 + 4] = c;
        uint4 uu;
        uu.x = pk2bf(a.x, a.y); uu.y = pk2bf(a.z, a.w);
        uu.z = pk2bf(c.x, c.y); uu.w = pk2bf(c.z, c.w);
        *(uint4*)&Qs[row][(dg ^ (row & 7)) * 8] = uu;
    }
    for (int idx = tid; idx < nbl * 16; idx += 256) {
        int row = idx >> 4, dg = idx & 15;
        size_t src = ((size_t)(cbase + row) * HH + h) * DD + dg * 4;
        *(float4*)&Kc[row][dg * 4] = *(const float4*)(kc + src);
        *(float4*)&Vc[row][dg * 4] = *(const float4*)(vc + src);
    }
    __syncthreads();

    // ---- phase 1: cmp scores fp32 (exact) ----
    {
        int qq = tid >> 3, jj = tid & 7;
        float4 qr[16];
        #pragma unroll
        for (int i = 0; i < 16; ++i) qr[i] = *(float4*)&Qf[qq][i * 4];
        #pragma unroll
        for (int jbase = 0; jbase < 2; ++jbase) {
            int j = jj + jbase * 8;
            if (j < nbl) {
                float s = 0.f;
                #pragma unroll
                for (int i = 0; i < 16; ++i) {
                    float4 kk = *(float4*)&Kc[j][i * 4];
                    s += qr[i].x * kk.x + qr[i].y * kk.y + qr[i].z * kk.z + qr[i].w * kk.w;
                }
                Sc[qq][j] = s;
            }
        }
    }
    __syncthreads();

    // ---- phase 2: rank -> selection bits + silu table ----
    {
        int qq = tid >> 3, jj = tid & 7;
        #pragma unroll
        for (int jbase = 0; jbase < 2; ++jbase) {
            int j = jj + jbase * 8;
            if (j < nbl) {
                float sj = Sc[qq][j];
                int rank = 0;
                for (int i = 0; i < nbl; ++i) {
                    float si = Sc[qq][i];
                    rank += (si > sj) || (si == sj && i < j);
                }
                selb[qq][j] = (unsigned char)(rank < SSEL);
                Ps[qq][j]   = silu_f(sj);
            } else if (j < 16) {
                selb[qq][j] = 0;
            }
        }
    }
    __syncthreads();

    // ---- phase 3a: assemble masks; phase 3b: cmp PV + gate + store ----
    if (tid < 32) {
        unsigned int m = 0;
        #pragma unroll
        for (int j = 0; j < 16; ++j) m |= ((unsigned int)selb[tid][j]) << j;
        Msk[tid] = m;
    }
    {
        int qq = tid >> 3, dg = tid & 7;
        float4 o0 = {0.f,0.f,0.f,0.f}, o1 = o0;
        for (int blk = 0; blk < nbl; ++blk) {
            float p = Ps[qq][blk];
            const float4* vr = (const float4*)&Vc[blk][dg * 8];
            float4 x = vr[0], y = vr[1];
            o0.x += p * x.x; o0.y += p * x.y; o0.z += p * x.z; o0.w += p * x.w;
            o1.x += p * y.x; o1.y += p * y.y; o1.z += p * y.z; o1.w += p * y.w;
        }
        float gv = gc[(size_t)(t0 + qq) * HH + h];
        o0.x *= gv; o0.y *= gv; o0.z *= gv; o0.w *= gv;
        o1.x *= gv; o1.y *= gv; o1.z *= gv; o1.w *= gv;
        float4* dst = (float4*)(out + (size_t)(t0 + qq) * STRIDE + h * DD + dg * 8);
        dst[0] = o0; dst[1] = o1;
    }
    __syncthreads();

    // ---- phase 4: slc attention via MFMA (round-6 verified engine) ----
    int w = tid >> 6, lane = tid & 63;
    int l15 = lane & 15, g = lane >> 4;

    unsigned int Msq[2];
    Msq[0] = Msk[l15];
    Msq[1] = Msk[16 + l15];

    f32x4 oacc[4][2];
    #pragma unroll
    for (int dt = 0; dt < 4; ++dt)
        #pragma unroll
        for (int qt = 0; qt < 2; ++qt)
            oacc[dt][qt] = (f32x4){0.f, 0.f, 0.f, 0.f};

    for (int kb = w; kb <= lb; kb += 4) {
        // stage this wave's K tile (bf16, XOR-swizzled)
        {
            int row = lane >> 1, hf = lane & 1;
            const float4* kp = (const float4*)(k + (size_t)(off + kb * BS + row) * STRIDE
                                               + h * DD + hf * 32);
            #pragma unroll
            for (int cc = 0; cc < 4; ++cc) {
                float4 x = kp[cc * 2], y = kp[cc * 2 + 1];
                uint4 uu;
                uu.x = pk2bf(x.x, x.y); uu.y = pk2bf(x.z, x.w);
                uu.z = pk2bf(y.x, y.y); uu.w = pk2bf(y.z, y.w);
                int c = hf * 4 + cc;
                *(uint4*)&Ks[w][row][(c ^ (row & 7)) * 8] = uu;
            }
        }

        // QK^T (swapped): S^T[k][q]
        bf16x8 a1[2][2], b1[2][2];
        #pragma unroll
        for (int ds = 0; ds < 2; ++ds)
            #pragma unroll
            for (int tt = 0; tt < 2; ++tt) {
                a1[tt][ds] = *(bf16x8*)&Ks[w][tt * 16 + l15][((g + ds * 4) ^ (l15 & 7)) * 8];
                b1[tt][ds] = *(bf16x8*)&Qs[tt * 16 + l15][((g + ds * 4) ^ (l15 & 7)) * 8];
            }
        f32x4 s[2][2];
        #pragma unroll
        for (int kt = 0; kt < 2; ++kt)
            #pragma unroll
            for (int qt = 0; qt < 2; ++qt) {
                s[kt][qt] = (f32x4){0.f, 0.f, 0.f, 0.f};
                s[kt][qt] = __builtin_amdgcn_mfma_f32_16x16x32_bf16(a1[kt][0], b1[qt][0], s[kt][qt], 0, 0, 0);
                s[kt][qt] = __builtin_amdgcn_mfma_f32_16x16x32_bf16(a1[kt][1], b1[qt][1], s[kt][qt], 0, 0, 0);
            }

        // mask + silu + pack P (bf16)
        #pragma unroll
        for (int kt = 0; kt < 2; ++kt)
            #pragma unroll
            for (int qt = 0; qt < 2; ++qt) {
                unsigned int mrow = Msq[qt];
                bool selbit = (mrow >> kb) & 1u;
                float pv[4];
                #pragma unroll
                for (int r = 0; r < 4; ++r) {
                    int k_l = kt * 16 + g * 4 + r;
                    int q_l = qt * 16 + l15;
                    bool ok = selbit && (kb < lb || k_l <= q_l);
                    pv[r] = ok ? silu_f(s[kt][qt][r]) : 0.f;
                }
                Pw[w][qt * 16 + l15][kt * 8 + g * 2 + 0] = pk2bf(pv[0], pv[1]);
                Pw[w][qt * 16 + l15][kt * 8 + g * 2 + 1] = pk2bf(pv[2], pv[3]);
            }

        bf16x8 b2[2];
        b2[0] = *(bf16x8*)&Pw[w][l15][g * 4];
        b2[1] = *(bf16x8*)&Pw[w][16 + l15][g * 4];

        // V^T fragments straight from global (L2-hit)
        const float* vg = v + (size_t)(off + kb * BS) * STRIDE + h * DD;
        bf16x8 a2[4];
        #pragma unroll
        for (int dt = 0; dt < 4; ++dt) {
            float tmp[8];
            #pragma unroll
            for (int j = 0; j < 8; ++j)
                tmp[j] = vg[(size_t)(g * 8 + j) * STRIDE + dt * 16 + l15];
            union { unsigned int u[4]; bf16x8 v8; } cu;
            cu.u[0] = pk2bf(tmp[0], tmp[1]);
            cu.u[1] = pk2bf(tmp[2], tmp[3]);
            cu.u[2] = pk2bf(tmp[4], tmp[5]);
            cu.u[3] = pk2bf(tmp[6], tmp[7]);
            a2[dt] = cu.v8;
        }

        #pragma unroll
        for (int dt = 0; dt < 4; ++dt)
            #pragma unroll
            for (int qt = 0; qt < 2; ++qt)
                oacc[dt][qt] = __builtin_amdgcn_mfma_f32_16x16x32_bf16(a2[dt], b2[qt], oacc[dt][qt], 0, 0, 0);
    }

    // transpose-store each wave's O^T partial to its LDS plane
    #pragma unroll
    for (int dt = 0; dt < 4; ++dt)
        #pragma unroll
        for (int qt = 0; qt < 2; ++qt)
            #pragma unroll
            for (int r = 0; r < 4; ++r)
                Op[w][qt * 16 + l15][dt * 16 + g * 4 + r] = oacc[dt][qt][r];
    __syncthreads();

    // combine 4 planes, gate, coalesced store
    {
        int qq = tid >> 3, dg = tid & 7;
        if (lb * BS + qq < n) {
            float gv = gs[(size_t)(t0 + qq) * HH + h];
            float o[8];
            #pragma unroll
            for (int i = 0; i < 8; ++i) {
                int d = dg * 8 + i;
                o[i] = (Op[0][qq][d] + Op[1][qq][d] + Op[2][qq][d] + Op[3][qq][d]) * gv;
            }
            float4* dst = (float4*)(out + (size_t)T * STRIDE + (size_t)(t0 + qq) * STRIDE
                                    + h * DD + dg * 8);
            dst[0] = (float4){o[0], o[1], o[2], o[3]};
            dst[1] = (float4){o[4], o[5], o[6], o[7]};
        }
    }
}

// ---------------------------------------------------------------------------
extern "C" void kernel_launch(void* const* d_in, const int* in_sizes, int n_in,
                              void* d_out, int out_size, void* d_ws, size_t ws_size,
                              hipStream_t stream) {
    const float* q    = (const float*)d_in[0];
    const float* k    = (const float*)d_in[1];
    const float* v    = (const float*)d_in[2];
    const float* gc   = (const float*)d_in[3];
    const float* gs   = (const float*)d_in[4];
    const int*   offs = (const int*)d_in[5];   // JAX x64-off: int32 on device

    int B = in_sizes[5] - 1;
    int T = out_size / (2 * STRIDE);
    int nbcap  = (T + BS - 1) / BS;
    int nqbcap = nbcap + B;

    size_t cmp_elems = (size_t)(nbcap + B) * STRIDE;
    float* kc = (float*)d_ws;
    float* vc = kc + cmp_elems;

    dim3 blk(256);
    int waves1 = B * nbcap * HH * 2;
    nsa_compress<<<dim3((unsigned)((waves1 * 64 + 255) / 256)), blk, 0, stream>>>(
        k, v, offs, B, nbcap, kc, vc);

    nsa_fused<<<dim3((unsigned)(nqbcap * HH)), blk, 0, stream>>>(
        q, k, v, gc, gs, offs, kc, vc, B, T, (float*)d_out);
}

// Round 8
// 22.309 us; speedup vs baseline: 2.8174x; 1.1944x over previous
//
#include <hip/hip_runtime.h>
#include <math.h>

#define HH 4
#define DD 64
#define BS 32
#define SSEL 4
#define STRIDE (HH * DD)

typedef __attribute__((ext_vector_type(8))) short bf16x8;
typedef __attribute__((ext_vector_type(4))) float f32x4;

__device__ __forceinline__ float silu_f(float x) { return x / (1.0f + __expf(-x)); }

__device__ __forceinline__ unsigned short f2bf(float f) {
    unsigned int x = __float_as_uint(f);
    return (unsigned short)((x + 0x7FFFu + ((x >> 16) & 1u)) >> 16);   // RNE
}
__device__ __forceinline__ unsigned int pk2bf(float a, float b) {
    return (unsigned int)f2bf(a) | ((unsigned int)f2bf(b) << 16);
}

// ---------------------------------------------------------------------------
// Kernel 1: block means of K and V. (verified)
__global__ __launch_bounds__(256) void nsa_compress(
        const float* __restrict__ kin, const float* __restrict__ vin,
        const int* __restrict__ offs, int B, int nbcap,
        float* __restrict__ kc, float* __restrict__ vc) {
    int wid  = (blockIdx.x * blockDim.x + threadIdx.x) >> 6;
    int lane = threadIdx.x & 63;
    if (wid >= B * nbcap * HH * 2) return;
    int kind = wid & 1;
    int rest = wid >> 1;
    int h    = rest % HH;
    int blk  = (rest / HH) % nbcap;
    int b    = rest / (HH * nbcap);
    int off  = offs[b];
    int n    = offs[b + 1] - off;
    int ncmp = (n + BS - 1) / BS;
    if (blk >= ncmp) return;
    int cbase = 0;
    for (int i = 0; i < b; ++i) cbase += (offs[i + 1] - offs[i] + BS - 1) / BS;

    int rg = lane >> 4, d16 = lane & 15;
    const float* src = kind ? vin : kin;
    const float4* sp = (const float4*)(src + (size_t)(off + blk * BS) * STRIDE + h * DD + d16 * 4);
    int rmax = min(BS, n - blk * BS);
    float4 acc = {0.f, 0.f, 0.f, 0.f};
    #pragma unroll
    for (int i = 0; i < 8; ++i) {
        int row = rg * 8 + i;
        if (row < rmax) {
            float4 x = sp[(size_t)row * (STRIDE / 4)];
            acc.x += x.x; acc.y += x.y; acc.z += x.z; acc.w += x.w;
        }
    }
    #pragma unroll
    for (int m = 16; m <= 32; m <<= 1) {
        acc.x += __shfl_xor(acc.x, m, 64);
        acc.y += __shfl_xor(acc.y, m, 64);
        acc.z += __shfl_xor(acc.z, m, 64);
        acc.w += __shfl_xor(acc.w, m, 64);
    }
    if (rg == 0) {
        float4 r;
        r.x = acc.x * (1.f / BS); r.y = acc.y * (1.f / BS);
        r.z = acc.z * (1.f / BS); r.w = acc.w * (1.f / BS);
        float* dst = (kind ? vc : kc) + ((size_t)(cbase + blk) * HH + h) * DD + d16 * 4;
        *(float4*)dst = r;
    }
}

// ---------------------------------------------------------------------------
// Kernel 2: fused per-(query-block, head) WG, 8 waves / 512 threads.
// cmp scores fp32 exact -> top-4 -> cmp PV -> MFMA slc (verified engine).
__global__ __launch_bounds__(512) void nsa_fused(
        const float* __restrict__ q, const float* __restrict__ k,
        const float* __restrict__ v, const float* __restrict__ gc,
        const float* __restrict__ gs, const int* __restrict__ offs,
        const float* __restrict__ kc, const float* __restrict__ vc,
        int B, int T, float* __restrict__ out) {
    __shared__ float Qf[32][68];                 // f32 scaled q
    __shared__ float Kc[16][68];                 // f32 kc tile
    __shared__ float Vc[16][64];                 // f32 vc tile
    __shared__ float Sc[32][17];                 // cmp scores
    __shared__ float Ps[32][17];                 // silu(scores)
    __shared__ unsigned char selb[32][16];
    __shared__ unsigned int  Msk[32];
    __shared__ unsigned short Qs[32][64];        // bf16, chunk-XOR swizzled
    __shared__ unsigned short Ks[8][32][64];     // per-wave K tile (32 KB)
    __shared__ unsigned int   Pw[8][32][20];     // per-wave P (bf16 pairs)
    __shared__ float          Op[4][32][68];     // O^T planes (2-step accum)

    int qbh = blockIdx.x;
    int h   = qbh & (HH - 1);
    int qb  = qbh / HH;

    int b = -1, lb = 0, cum = 0, off = 0, n = 0;
    for (int i = 0; i < B; ++i) {
        int o0 = offs[i], o1 = offs[i + 1];
        int nbi = (o1 - o0 + BS - 1) / BS;
        if (qb < cum + nbi) { b = i; lb = qb - cum; off = o0; n = o1 - o0; break; }
        cum += nbi;
    }
    if (b < 0) return;
    int cbase = cum;
    int t0  = off + lb * BS;
    int nbl = lb + 1;                // <= 16 (seqlen <= 512)
    const float scale = 0.125f;
    int tid = threadIdx.x;
    int w = tid >> 6, lane = tid & 63;
    int l15 = lane & 15, g = lane >> 4;

    // ---- T14 issue-early: first slc iteration's K tile + V gather ----
    float4 K0[8];
    float  tv0[4][8];
    bool have0 = (w <= lb);
    if (have0) {
        int row = lane >> 1, hf = lane & 1;
        const float4* kp = (const float4*)(k + (size_t)(off + w * BS + row) * STRIDE
                                           + h * DD + hf * 32);
        #pragma unroll
        for (int cc = 0; cc < 8; ++cc) K0[cc] = kp[cc];
        const float* vg = v + (size_t)(off + w * BS) * STRIDE + h * DD;
        #pragma unroll
        for (int dt = 0; dt < 4; ++dt)
            #pragma unroll
            for (int j = 0; j < 8; ++j)
                tv0[dt][j] = vg[(size_t)(g * 8 + j) * STRIDE + dt * 16 + l15];
    }

    // ---- phase 0: stage Q (f32 + bf16 swizzled) and Kc/Vc tiles ----
    {
        int row = tid >> 4, dg = tid & 15;
        int trow = min(t0 + row, T - 1);
        float4 a = *(const float4*)(q + (size_t)trow * STRIDE + h * DD + dg * 4);
        a.x *= scale; a.y *= scale; a.z *= scale; a.w *= scale;
        *(float4*)&Qf[row][dg * 4] = a;
        uint2 uu = { pk2bf(a.x, a.y), pk2bf(a.z, a.w) };
        *(uint2*)&Qs[row][(((dg >> 1) ^ (row & 7)) * 8) + (dg & 1) * 4] = uu;
    }
    for (int idx = tid; idx < nbl * 16; idx += 512) {
        int row = idx >> 4, dg = idx & 15;
        size_t src = ((size_t)(cbase + row) * HH + h) * DD + dg * 4;
        *(float4*)&Kc[row][dg * 4] = *(const float4*)(kc + src);
        *(float4*)&Vc[row][dg * 4] = *(const float4*)(vc + src);
    }
    __syncthreads();

    // ---- phase 1: cmp scores fp32 (exact), one (q, blk) per thread ----
    {
        int qq = tid >> 4, j = tid & 15;
        if (j < nbl) {
            float s = 0.f;
            #pragma unroll
            for (int i = 0; i < 16; ++i) {
                float4 qv = *(float4*)&Qf[qq][i * 4];
                float4 kk = *(float4*)&Kc[j][i * 4];
                s += qv.x * kk.x + qv.y * kk.y + qv.z * kk.z + qv.w * kk.w;
            }
            Sc[qq][j] = s;
        }
    }
    __syncthreads();

    // ---- phase 2: rank -> selection bits + silu table ----
    {
        int qq = tid >> 4, j = tid & 15;
        if (j < nbl) {
            float sj = Sc[qq][j];
            int rank = 0;
            for (int i = 0; i < nbl; ++i) {
                float si = Sc[qq][i];
                rank += (si > sj) || (si == sj && i < j);
            }
            selb[qq][j] = (unsigned char)(rank < SSEL);
            Ps[qq][j]   = silu_f(sj);
        } else {
            selb[qq][j] = 0;
        }
    }
    __syncthreads();

    // ---- phase 3: masks + cmp PV + gc gate + store o_cmp ----
    if (tid < 32) {
        unsigned int m = 0;
        #pragma unroll
        for (int j = 0; j < 16; ++j) m |= ((unsigned int)selb[tid][j]) << j;
        Msk[tid] = m;
    }
    {
        int qq = tid >> 4, dg = tid & 15;
        float4 o = {0.f, 0.f, 0.f, 0.f};
        for (int blk = 0; blk < nbl; ++blk) {
            float p = Ps[qq][blk];
            float4 vv = *(float4*)&Vc[blk][dg * 4];
            o.x += p * vv.x; o.y += p * vv.y; o.z += p * vv.z; o.w += p * vv.w;
        }
        if (lb * BS + qq < n) {
            float gv = gc[(size_t)(t0 + qq) * HH + h];
            o.x *= gv; o.y *= gv; o.z *= gv; o.w *= gv;
            *(float4*)(out + (size_t)(t0 + qq) * STRIDE + h * DD + dg * 4) = o;
        }
    }
    __syncthreads();

    // ---- phase 4: slc attention via MFMA (verified engine), kb += 8 ----
    unsigned int Msq[2];
    Msq[0] = Msk[l15];
    Msq[1] = Msk[16 + l15];

    f32x4 oacc[4][2];
    #pragma unroll
    for (int dt = 0; dt < 4; ++dt)
        #pragma unroll
        for (int qt = 0; qt < 2; ++qt)
            oacc[dt][qt] = (f32x4){0.f, 0.f, 0.f, 0.f};

    #pragma unroll 1
    for (int kb = w; kb <= lb; kb += 8) {
        // K tile (regs -> bf16 swizzled LDS)
        int row = lane >> 1, hf = lane & 1;
        float4 kx[8];
        float  tv[4][8];
        if (kb == w) {
            #pragma unroll
            for (int cc = 0; cc < 8; ++cc) kx[cc] = K0[cc];
            #pragma unroll
            for (int dt = 0; dt < 4; ++dt)
                #pragma unroll
                for (int j = 0; j < 8; ++j) tv[dt][j] = tv0[dt][j];
        } else {
            const float4* kp = (const float4*)(k + (size_t)(off + kb * BS + row) * STRIDE
                                               + h * DD + hf * 32);
            #pragma unroll
            for (int cc = 0; cc < 8; ++cc) kx[cc] = kp[cc];
            const float* vg = v + (size_t)(off + kb * BS) * STRIDE + h * DD;
            #pragma unroll
            for (int dt = 0; dt < 4; ++dt)
                #pragma unroll
                for (int j = 0; j < 8; ++j)
                    tv[dt][j] = vg[(size_t)(g * 8 + j) * STRIDE + dt * 16 + l15];
        }
        #pragma unroll
        for (int cc = 0; cc < 4; ++cc) {
            float4 x = kx[cc * 2], y = kx[cc * 2 + 1];
            uint4 uu;
            uu.x = pk2bf(x.x, x.y); uu.y = pk2bf(x.z, x.w);
            uu.z = pk2bf(y.x, y.y); uu.w = pk2bf(y.z, y.w);
            int c = hf * 4 + cc;
            *(uint4*)&Ks[w][row][(c ^ (row & 7)) * 8] = uu;
        }

        // QK^T (swapped): S^T[k][q]
        bf16x8 a1[2][2], b1[2][2];
        #pragma unroll
        for (int ds = 0; ds < 2; ++ds)
            #pragma unroll
            for (int tt = 0; tt < 2; ++tt) {
                a1[tt][ds] = *(bf16x8*)&Ks[w][tt * 16 + l15][((g + ds * 4) ^ (l15 & 7)) * 8];
                b1[tt][ds] = *(bf16x8*)&Qs[tt * 16 + l15][((g + ds * 4) ^ (l15 & 7)) * 8];
            }
        f32x4 s[2][2];
        #pragma unroll
        for (int kt = 0; kt < 2; ++kt)
            #pragma unroll
            for (int qt = 0; qt < 2; ++qt) {
                s[kt][qt] = (f32x4){0.f, 0.f, 0.f, 0.f};
                s[kt][qt] = __builtin_amdgcn_mfma_f32_16x16x32_bf16(a1[kt][0], b1[qt][0], s[kt][qt], 0, 0, 0);
                s[kt][qt] = __builtin_amdgcn_mfma_f32_16x16x32_bf16(a1[kt][1], b1[qt][1], s[kt][qt], 0, 0, 0);
            }

        // mask + silu + pack P (bf16)
        #pragma unroll
        for (int kt = 0; kt < 2; ++kt)
            #pragma unroll
            for (int qt = 0; qt < 2; ++qt) {
                unsigned int mrow = Msq[qt];
                bool selbit = (mrow >> kb) & 1u;
                float pv[4];
                #pragma unroll
                for (int r = 0; r < 4; ++r) {
                    int k_l = kt * 16 + g * 4 + r;
                    int q_l = qt * 16 + l15;
                    bool ok = selbit && (kb < lb || k_l <= q_l);
                    pv[r] = ok ? silu_f(s[kt][qt][r]) : 0.f;
                }
                Pw[w][qt * 16 + l15][kt * 8 + g * 2 + 0] = pk2bf(pv[0], pv[1]);
                Pw[w][qt * 16 + l15][kt * 8 + g * 2 + 1] = pk2bf(pv[2], pv[3]);
            }

        bf16x8 b2[2];
        b2[0] = *(bf16x8*)&Pw[w][l15][g * 4];
        b2[1] = *(bf16x8*)&Pw[w][16 + l15][g * 4];

        bf16x8 a2[4];
        #pragma unroll
        for (int dt = 0; dt < 4; ++dt) {
            union { unsigned int u[4]; bf16x8 v8; } cu;
            cu.u[0] = pk2bf(tv[dt][0], tv[dt][1]);
            cu.u[1] = pk2bf(tv[dt][2], tv[dt][3]);
            cu.u[2] = pk2bf(tv[dt][4], tv[dt][5]);
            cu.u[3] = pk2bf(tv[dt][6], tv[dt][7]);
            a2[dt] = cu.v8;
        }

        #pragma unroll
        for (int dt = 0; dt < 4; ++dt)
            #pragma unroll
            for (int qt = 0; qt < 2; ++qt)
                oacc[dt][qt] = __builtin_amdgcn_mfma_f32_16x16x32_bf16(a2[dt], b2[qt], oacc[dt][qt], 0, 0, 0);
    }

    // ---- phase 5: two-step plane accumulation ----
    if (w < 4) {
        #pragma unroll
        for (int dt = 0; dt < 4; ++dt)
            #pragma unroll
            for (int qt = 0; qt < 2; ++qt)
                #pragma unroll
                for (int r = 0; r < 4; ++r)
                    Op[w][qt * 16 + l15][dt * 16 + g * 4 + r] = oacc[dt][qt][r];
    }
    __syncthreads();
    if (w >= 4) {
        #pragma unroll
        for (int dt = 0; dt < 4; ++dt)
            #pragma unroll
            for (int qt = 0; qt < 2; ++qt)
                #pragma unroll
                for (int r = 0; r < 4; ++r)
                    Op[w - 4][qt * 16 + l15][dt * 16 + g * 4 + r] += oacc[dt][qt][r];
    }
    __syncthreads();

    // ---- phase 6: combine planes, gate, store o_slc ----
    {
        int qq = tid >> 4, dg = tid & 15;
        if (lb * BS + qq < n) {
            float gv = gs[(size_t)(t0 + qq) * HH + h];
            float o[4];
            #pragma unroll
            for (int i = 0; i < 4; ++i) {
                int d = dg * 4 + i;
                o[i] = (Op[0][qq][d] + Op[1][qq][d] + Op[2][qq][d] + Op[3][qq][d]) * gv;
            }
            *(float4*)(out + (size_t)T * STRIDE + (size_t)(t0 + qq) * STRIDE + h * DD + dg * 4)
                = (float4){o[0], o[1], o[2], o[3]};
        }
    }
}

// ---------------------------------------------------------------------------
extern "C" void kernel_launch(void* const* d_in, const int* in_sizes, int n_in,
                              void* d_out, int out_size, void* d_ws, size_t ws_size,
                              hipStream_t stream) {
    const float* q    = (const float*)d_in[0];
    const float* k    = (const float*)d_in[1];
    const float* v    = (const float*)d_in[2];
    const float* gc   = (const float*)d_in[3];
    const float* gs   = (const float*)d_in[4];
    const int*   offs = (const int*)d_in[5];   // JAX x64-off: int32 on device

    int B = in_sizes[5] - 1;
    int T = out_size / (2 * STRIDE);
    int nbcap  = (T + BS - 1) / BS;
    int nqbcap = nbcap + B;

    size_t cmp_elems = (size_t)(nbcap + B) * STRIDE;
    float* kc = (float*)d_ws;
    float* vc = kc + cmp_elems;

    int waves1 = B * nbcap * HH * 2;
    nsa_compress<<<dim3((unsigned)((waves1 * 64 + 255) / 256)), dim3(256), 0, stream>>>(
        k, v, offs, B, nbcap, kc, vc);

    nsa_fused<<<dim3((unsigned)(nqbcap * HH)), dim3(512), 0, stream>>>(
        q, k, v, gc, gs, offs, kc, vc, B, T, (float*)d_out);
}

// Round 9
// 20.704 us; speedup vs baseline: 3.0358x; 1.0775x over previous
//
#include <hip/hip_runtime.h>
#include <math.h>

#define HH 4
#define DD 64
#define BS 32
#define SSEL 4
#define STRIDE (HH * DD)

typedef __attribute__((ext_vector_type(8))) short bf16x8;
typedef __attribute__((ext_vector_type(4))) float f32x4;

__device__ __forceinline__ float silu_f(float x) { return x / (1.0f + __expf(-x)); }

__device__ __forceinline__ unsigned short f2bf(float f) {
    unsigned int x = __float_as_uint(f);
    return (unsigned short)((x + 0x7FFFu + ((x >> 16) & 1u)) >> 16);   // RNE
}
__device__ __forceinline__ unsigned int pk2bf(float a, float b) {
    return (unsigned int)f2bf(a) | ((unsigned int)f2bf(b) << 16);
}

// ---------------------------------------------------------------------------
// Single fused kernel. One WG (8 waves / 512 threads) per (query-block, head):
//   in-WG fp32 block means -> fp32 cmp scores (exact selection) -> top-4 ->
//   cmp PV -> MFMA bf16 slc attention (verified engine, both tiles prefetched).
__global__ __launch_bounds__(512) void nsa_all(
        const float* __restrict__ q, const float* __restrict__ k,
        const float* __restrict__ v, const float* __restrict__ gc,
        const float* __restrict__ gs, const int* __restrict__ offs,
        int B, int T, float* __restrict__ out) {
    __shared__ float Qf[32][68];                 // f32 scaled q
    __shared__ float Kc[16][68];                 // f32 block-mean K
    __shared__ float Vc[16][64];                 // f32 block-mean V
    __shared__ float Sc[32][17];                 // cmp scores
    __shared__ float Ps[32][17];                 // silu(scores)
    __shared__ unsigned char selb[32][16];
    __shared__ unsigned int  Msk[32];
    __shared__ unsigned short Qs[32][64];        // bf16, chunk-XOR swizzled
    __shared__ unsigned short Ks[8][32][64];     // per-wave K tile
    __shared__ unsigned int   Pw[8][32][20];     // per-wave P (bf16 pairs)
    __shared__ float          Op[4][32][68];     // O^T planes (2-step accum)

    int qbh = blockIdx.x;
    int h   = qbh & (HH - 1);
    int qb  = qbh / HH;

    int b = -1, lb = 0, cum = 0, off = 0, n = 0;
    for (int i = 0; i < B; ++i) {
        int o0 = offs[i], o1 = offs[i + 1];
        int nbi = (o1 - o0 + BS - 1) / BS;
        if (qb < cum + nbi) { b = i; lb = qb - cum; off = o0; n = o1 - o0; break; }
        cum += nbi;
    }
    if (b < 0) return;
    int t0  = off + lb * BS;
    int nbl = lb + 1;                // <= 16 (seqlen <= 512)
    const float scale = 0.125f;
    int tid = threadIdx.x;
    int w = tid >> 6, lane = tid & 63;
    int l15 = lane & 15, g = lane >> 4;

    // ---- T14 issue-early: BOTH slc iterations' K tiles + V gathers ----
    int krow = lane >> 1, khf = lane & 1;
    float4 K0[8], K1[8];
    float  tv0[4][8], tv1[4][8];
    bool have0 = (w <= lb);
    bool have1 = (w + 8 <= lb);
    if (have0) {
        const float4* kp = (const float4*)(k + (size_t)(off + w * BS + krow) * STRIDE
                                           + h * DD + khf * 32);
        #pragma unroll
        for (int cc = 0; cc < 8; ++cc) K0[cc] = kp[cc];
        const float* vg = v + (size_t)(off + w * BS) * STRIDE + h * DD;
        #pragma unroll
        for (int dt = 0; dt < 4; ++dt)
            #pragma unroll
            for (int j = 0; j < 8; ++j)
                tv0[dt][j] = vg[(size_t)(g * 8 + j) * STRIDE + dt * 16 + l15];
    }
    if (have1) {
        const float4* kp = (const float4*)(k + (size_t)(off + (w + 8) * BS + krow) * STRIDE
                                           + h * DD + khf * 32);
        #pragma unroll
        for (int cc = 0; cc < 8; ++cc) K1[cc] = kp[cc];
        const float* vg = v + (size_t)(off + (w + 8) * BS) * STRIDE + h * DD;
        #pragma unroll
        for (int dt = 0; dt < 4; ++dt)
            #pragma unroll
            for (int j = 0; j < 8; ++j)
                tv1[dt][j] = vg[(size_t)(g * 8 + j) * STRIDE + dt * 16 + l15];
    }

    // ---- phase 0a: stage Q (f32 + bf16 swizzled) ----
    {
        int row = tid >> 4, dg = tid & 15;
        int trow = min(t0 + row, T - 1);
        float4 a = *(const float4*)(q + (size_t)trow * STRIDE + h * DD + dg * 4);
        a.x *= scale; a.y *= scale; a.z *= scale; a.w *= scale;
        *(float4*)&Qf[row][dg * 4] = a;
        uint2 uu = { pk2bf(a.x, a.y), pk2bf(a.z, a.w) };
        *(uint2*)&Qs[row][(((dg >> 1) ^ (row & 7)) * 8) + (dg & 1) * 4] = uu;
    }

    // ---- phase 0b: in-WG block means of K and V (fp32, exact path) ----
    for (int idx = tid; idx < nbl * 64; idx += 512) {
        int j = idx >> 6, d = idx & 63;
        const float* kp = k + (size_t)(off + j * BS) * STRIDE + h * DD + d;
        const float* vp = v + (size_t)(off + j * BS) * STRIDE + h * DD + d;
        float ks = 0.f, vs = 0.f;
        #pragma unroll
        for (int r = 0; r < BS; ++r) {
            ks += kp[(size_t)r * STRIDE];
            vs += vp[(size_t)r * STRIDE];
        }
        Kc[j][d] = ks * (1.f / BS);
        Vc[j][d] = vs * (1.f / BS);
    }
    __syncthreads();

    // ---- phase 1: cmp scores fp32 (exact), one (q, blk) per thread ----
    {
        int qq = tid >> 4, j = tid & 15;
        if (j < nbl) {
            float s = 0.f;
            #pragma unroll
            for (int i = 0; i < 16; ++i) {
                float4 qv = *(float4*)&Qf[qq][i * 4];
                float4 kk = *(float4*)&Kc[j][i * 4];
                s += qv.x * kk.x + qv.y * kk.y + qv.z * kk.z + qv.w * kk.w;
            }
            Sc[qq][j] = s;
        }
    }
    __syncthreads();

    // ---- phase 2: rank -> selection bits + silu table ----
    {
        int qq = tid >> 4, j = tid & 15;
        if (j < nbl) {
            float sj = Sc[qq][j];
            int rank = 0;
            for (int i = 0; i < nbl; ++i) {
                float si = Sc[qq][i];
                rank += (si > sj) || (si == sj && i < j);
            }
            selb[qq][j] = (unsigned char)(rank < SSEL);
            Ps[qq][j]   = silu_f(sj);
        } else {
            selb[qq][j] = 0;
        }
    }
    __syncthreads();

    // ---- phase 3: masks + cmp PV + gc gate + store o_cmp ----
    if (tid < 32) {
        unsigned int m = 0;
        #pragma unroll
        for (int j = 0; j < 16; ++j) m |= ((unsigned int)selb[tid][j]) << j;
        Msk[tid] = m;
    }
    {
        int qq = tid >> 4, dg = tid & 15;
        float4 o = {0.f, 0.f, 0.f, 0.f};
        for (int blk = 0; blk < nbl; ++blk) {
            float p = Ps[qq][blk];
            float4 vv = *(float4*)&Vc[blk][dg * 4];
            o.x += p * vv.x; o.y += p * vv.y; o.z += p * vv.z; o.w += p * vv.w;
        }
        if (lb * BS + qq < n) {
            float gv = gc[(size_t)(t0 + qq) * HH + h];
            o.x *= gv; o.y *= gv; o.z *= gv; o.w *= gv;
            *(float4*)(out + (size_t)(t0 + qq) * STRIDE + h * DD + dg * 4) = o;
        }
    }
    __syncthreads();

    // ---- phase 4: slc attention via MFMA (verified engine), 2 steps ----
    unsigned int Msq[2];
    Msq[0] = Msk[l15];
    Msq[1] = Msk[16 + l15];

    f32x4 oacc[4][2];
    #pragma unroll
    for (int dt = 0; dt < 4; ++dt)
        #pragma unroll
        for (int qt = 0; qt < 2; ++qt)
            oacc[dt][qt] = (f32x4){0.f, 0.f, 0.f, 0.f};

#define SLC_STEP(KB, KX, TV)                                                          \
    {                                                                                 \
        const int kb = (KB);                                                          \
        /* K tile regs -> bf16 swizzled wave-private LDS */                           \
        _Pragma("unroll")                                                             \
        for (int cc = 0; cc < 4; ++cc) {                                              \
            float4 x = KX[cc * 2], y = KX[cc * 2 + 1];                                \
            uint4 uu;                                                                 \
            uu.x = pk2bf(x.x, x.y); uu.y = pk2bf(x.z, x.w);                           \
            uu.z = pk2bf(y.x, y.y); uu.w = pk2bf(y.z, y.w);                           \
            int c = khf * 4 + cc;                                                     \
            *(uint4*)&Ks[w][krow][(c ^ (krow & 7)) * 8] = uu;                         \
        }                                                                             \
        /* QK^T (swapped): S^T[k][q] */                                               \
        bf16x8 a1[2][2], b1[2][2];                                                    \
        _Pragma("unroll")                                                             \
        for (int ds = 0; ds < 2; ++ds)                                                \
            _Pragma("unroll")                                                         \
            for (int tt = 0; tt < 2; ++tt) {                                          \
                a1[tt][ds] = *(bf16x8*)&Ks[w][tt * 16 + l15][((g + ds * 4) ^ (l15 & 7)) * 8]; \
                b1[tt][ds] = *(bf16x8*)&Qs[tt * 16 + l15][((g + ds * 4) ^ (l15 & 7)) * 8];    \
            }                                                                         \
        f32x4 s[2][2];                                                                \
        _Pragma("unroll")                                                             \
        for (int kt = 0; kt < 2; ++kt)                                                \
            _Pragma("unroll")                                                         \
            for (int qt = 0; qt < 2; ++qt) {                                          \
                s[kt][qt] = (f32x4){0.f, 0.f, 0.f, 0.f};                              \
                s[kt][qt] = __builtin_amdgcn_mfma_f32_16x16x32_bf16(a1[kt][0], b1[qt][0], s[kt][qt], 0, 0, 0); \
                s[kt][qt] = __builtin_amdgcn_mfma_f32_16x16x32_bf16(a1[kt][1], b1[qt][1], s[kt][qt], 0, 0, 0); \
            }                                                                         \
        /* mask + silu + pack P (bf16) */                                             \
        _Pragma("unroll")                                                             \
        for (int kt = 0; kt < 2; ++kt)                                                \
            _Pragma("unroll")                                                         \
            for (int qt = 0; qt < 2; ++qt) {                                          \
                bool selbit = (Msq[qt] >> kb) & 1u;                                   \
                float pv[4];                                                          \
                _Pragma("unroll")                                                     \
                for (int r = 0; r < 4; ++r) {                                         \
                    int k_l = kt * 16 + g * 4 + r;                                    \
                    int q_l = qt * 16 + l15;                                          \
                    bool ok = selbit && (kb < lb || k_l <= q_l);                      \
                    pv[r] = ok ? silu_f(s[kt][qt][r]) : 0.f;                          \
                }                                                                     \
                Pw[w][qt * 16 + l15][kt * 8 + g * 2 + 0] = pk2bf(pv[0], pv[1]);       \
                Pw[w][qt * 16 + l15][kt * 8 + g * 2 + 1] = pk2bf(pv[2], pv[3]);       \
            }                                                                         \
        bf16x8 b2[2];                                                                 \
        b2[0] = *(bf16x8*)&Pw[w][l15][g * 4];                                         \
        b2[1] = *(bf16x8*)&Pw[w][16 + l15][g * 4];                                    \
        bf16x8 a2[4];                                                                 \
        _Pragma("unroll")                                                             \
        for (int dt = 0; dt < 4; ++dt) {                                              \
            union { unsigned int u[4]; bf16x8 v8; } cu;                               \
            cu.u[0] = pk2bf(TV[dt][0], TV[dt][1]);                                    \
            cu.u[1] = pk2bf(TV[dt][2], TV[dt][3]);                                    \
            cu.u[2] = pk2bf(TV[dt][4], TV[dt][5]);                                    \
            cu.u[3] = pk2bf(TV[dt][6], TV[dt][7]);                                    \
            a2[dt] = cu.v8;                                                           \
        }                                                                             \
        _Pragma("unroll")                                                             \
        for (int dt = 0; dt < 4; ++dt)                                                \
            _Pragma("unroll")                                                         \
            for (int qt = 0; qt < 2; ++qt)                                            \
                oacc[dt][qt] = __builtin_amdgcn_mfma_f32_16x16x32_bf16(a2[dt], b2[qt], oacc[dt][qt], 0, 0, 0); \
    }

    if (have0) SLC_STEP(w, K0, tv0)
    if (have1) SLC_STEP(w + 8, K1, tv1)
#undef SLC_STEP

    // ---- phase 5: two-step plane accumulation ----
    if (w < 4) {
        #pragma unroll
        for (int dt = 0; dt < 4; ++dt)
            #pragma unroll
            for (int qt = 0; qt < 2; ++qt)
                #pragma unroll
                for (int r = 0; r < 4; ++r)
                    Op[w][qt * 16 + l15][dt * 16 + g * 4 + r] = oacc[dt][qt][r];
    }
    __syncthreads();
    if (w >= 4) {
        #pragma unroll
        for (int dt = 0; dt < 4; ++dt)
            #pragma unroll
            for (int qt = 0; qt < 2; ++qt)
                #pragma unroll
                for (int r = 0; r < 4; ++r)
                    Op[w - 4][qt * 16 + l15][dt * 16 + g * 4 + r] += oacc[dt][qt][r];
    }
    __syncthreads();

    // ---- phase 6: combine planes, gate, store o_slc ----
    {
        int qq = tid >> 4, dg = tid & 15;
        if (lb * BS + qq < n) {
            float gv = gs[(size_t)(t0 + qq) * HH + h];
            float o[4];
            #pragma unroll
            for (int i = 0; i < 4; ++i) {
                int d = dg * 4 + i;
                o[i] = (Op[0][qq][d] + Op[1][qq][d] + Op[2][qq][d] + Op[3][qq][d]) * gv;
            }
            *(float4*)(out + (size_t)T * STRIDE + (size_t)(t0 + qq) * STRIDE + h * DD + dg * 4)
                = (float4){o[0], o[1], o[2], o[3]};
        }
    }
}

// ---------------------------------------------------------------------------
extern "C" void kernel_launch(void* const* d_in, const int* in_sizes, int n_in,
                              void* d_out, int out_size, void* d_ws, size_t ws_size,
                              hipStream_t stream) {
    const float* q    = (const float*)d_in[0];
    const float* k    = (const float*)d_in[1];
    const float* v    = (const float*)d_in[2];
    const float* gc   = (const float*)d_in[3];
    const float* gs   = (const float*)d_in[4];
    const int*   offs = (const int*)d_in[5];   // JAX x64-off: int32 on device

    int B = in_sizes[5] - 1;
    int T = out_size / (2 * STRIDE);
    int nbcap  = (T + BS - 1) / BS;
    int nqbcap = nbcap + B;                    // upper bound on query blocks

    nsa_all<<<dim3((unsigned)(nqbcap * HH)), dim3(512), 0, stream>>>(
        q, k, v, gc, gs, offs, B, T, (float*)d_out);
}

// Round 10
// 19.603 us; speedup vs baseline: 3.2064x; 1.0562x over previous
//
#include <hip/hip_runtime.h>
#include <math.h>

#define HH 4
#define DD 64
#define BS 32
#define SSEL 4
#define STRIDE (HH * DD)

typedef __attribute__((ext_vector_type(8))) short bf16x8;
typedef __attribute__((ext_vector_type(4))) float f32x4;

__device__ __forceinline__ float silu_f(float x) { return x / (1.0f + __expf(-x)); }

__device__ __forceinline__ unsigned short f2bf(float f) {
    unsigned int x = __float_as_uint(f);
    return (unsigned short)((x + 0x7FFFu + ((x >> 16) & 1u)) >> 16);   // RNE
}
__device__ __forceinline__ unsigned int pk2bf(float a, float b) {
    return (unsigned int)f2bf(a) | ((unsigned int)f2bf(b) << 16);
}

// ---------------------------------------------------------------------------
// Single fused kernel. One WG (8 waves / 512 threads) per (query-block, head).
__global__ __launch_bounds__(512, 2) void nsa_all(
        const float* __restrict__ q, const float* __restrict__ k,
        const float* __restrict__ v, const float* __restrict__ gc,
        const float* __restrict__ gs, const int* __restrict__ offs,
        int B, int T, float* __restrict__ out) {
    __shared__ float Qf[32][68];                 // f32 scaled q
    __shared__ float Kc[16][68];                 // f32 block-mean K
    __shared__ float Vc[16][64];                 // f32 block-mean V
    __shared__ float Sc[32][17];                 // cmp scores
    __shared__ float Ps[32][17];                 // silu(scores)
    __shared__ unsigned char selb[32][16];
    __shared__ unsigned int  Msk[32];
    __shared__ unsigned short Qs[32][64];        // bf16, chunk-XOR swizzled
    __shared__ unsigned short Ks[8][32][64];     // per-wave K tile
    __shared__ unsigned int   Pw[8][32][20];     // per-wave P (bf16 pairs)
    __shared__ float          Op[4][32][68];     // O^T planes (2-step accum)

    int qbh = blockIdx.x;
    int h   = qbh & (HH - 1);
    int qb  = qbh / HH;

    int b = -1, lb = 0, cum = 0, off = 0, n = 0;
    for (int i = 0; i < B; ++i) {
        int o0 = offs[i], o1 = offs[i + 1];
        int nbi = (o1 - o0 + BS - 1) / BS;
        if (qb < cum + nbi) { b = i; lb = qb - cum; off = o0; n = o1 - o0; break; }
        cum += nbi;
    }
    if (b < 0) return;
    int t0  = off + lb * BS;
    int nbl = lb + 1;                // <= 16 (seqlen <= 512)
    const float scale = 0.125f;
    int tid = threadIdx.x;
    int w = tid >> 6, lane = tid & 63;
    int l15 = lane & 15, g = lane >> 4;
    int krow = lane >> 1, khf = lane & 1;

    // ---- T14 issue-early: FIRST slc tile only (K + V gather) ----
    float4 K0[8];
    float  tv0[4][8];
    bool have0 = (w <= lb);
    bool have1 = (w + 8 <= lb);
    if (have0) {
        const float4* kp = (const float4*)(k + (size_t)(off + w * BS + krow) * STRIDE
                                           + h * DD + khf * 32);
        #pragma unroll
        for (int cc = 0; cc < 8; ++cc) K0[cc] = kp[cc];
        const float* vg = v + (size_t)(off + w * BS) * STRIDE + h * DD;
        #pragma unroll
        for (int dt = 0; dt < 4; ++dt)
            #pragma unroll
            for (int j = 0; j < 8; ++j)
                tv0[dt][j] = vg[(size_t)(g * 8 + j) * STRIDE + dt * 16 + l15];
    }

    // ---- phase 0a: stage Q (f32 + bf16 swizzled) ----
    {
        int row = tid >> 4, dg = tid & 15;
        int trow = min(t0 + row, T - 1);
        float4 a = *(const float4*)(q + (size_t)trow * STRIDE + h * DD + dg * 4);
        a.x *= scale; a.y *= scale; a.z *= scale; a.w *= scale;
        *(float4*)&Qf[row][dg * 4] = a;
        uint2 uu = { pk2bf(a.x, a.y), pk2bf(a.z, a.w) };
        *(uint2*)&Qs[row][(((dg >> 1) ^ (row & 7)) * 8) + (dg & 1) * 4] = uu;
    }

    // ---- phase 0b: in-WG block means, one float4 column per thread ----
    if (tid < nbl * 32) {
        int j = tid >> 5, rest = tid & 31, kind = rest >> 4, d4 = rest & 15;
        const float* base = (kind ? v : k) + (size_t)(off + j * BS) * STRIDE + h * DD + d4 * 4;
        float4 acc = {0.f, 0.f, 0.f, 0.f};
        #pragma unroll
        for (int r = 0; r < BS; ++r) {
            float4 x = *(const float4*)(base + (size_t)r * STRIDE);
            acc.x += x.x; acc.y += x.y; acc.z += x.z; acc.w += x.w;
        }
        acc.x *= (1.f / BS); acc.y *= (1.f / BS); acc.z *= (1.f / BS); acc.w *= (1.f / BS);
        if (kind) *(float4*)&Vc[j][d4 * 4] = acc;
        else      *(float4*)&Kc[j][d4 * 4] = acc;
    }
    __syncthreads();

    // ---- phase 1: cmp scores fp32 (exact), one (q, blk) per thread ----
    {
        int qq = tid >> 4, j = tid & 15;
        if (j < nbl) {
            float s = 0.f;
            #pragma unroll
            for (int i = 0; i < 16; ++i) {
                float4 qv = *(float4*)&Qf[qq][i * 4];
                float4 kk = *(float4*)&Kc[j][i * 4];
                s += qv.x * kk.x + qv.y * kk.y + qv.z * kk.z + qv.w * kk.w;
            }
            Sc[qq][j] = s;
        }
    }
    __syncthreads();

    // ---- phase 2: rank -> selection bits + silu table ----
    {
        int qq = tid >> 4, j = tid & 15;
        if (j < nbl) {
            float sj = Sc[qq][j];
            int rank = 0;
            for (int i = 0; i < nbl; ++i) {
                float si = Sc[qq][i];
                rank += (si > sj) || (si == sj && i < j);
            }
            selb[qq][j] = (unsigned char)(rank < SSEL);
            Ps[qq][j]   = silu_f(sj);
        } else {
            selb[qq][j] = 0;
        }
    }
    __syncthreads();

    // ---- phase 3: masks + cmp PV + gc gate + store o_cmp ----
    if (tid < 32) {
        unsigned int m = 0;
        #pragma unroll
        for (int j = 0; j < 16; ++j) m |= ((unsigned int)selb[tid][j]) << j;
        Msk[tid] = m;
    }
    {
        int qq = tid >> 4, dg = tid & 15;
        float4 o = {0.f, 0.f, 0.f, 0.f};
        for (int blk = 0; blk < nbl; ++blk) {
            float p = Ps[qq][blk];
            float4 vv = *(float4*)&Vc[blk][dg * 4];
            o.x += p * vv.x; o.y += p * vv.y; o.z += p * vv.z; o.w += p * vv.w;
        }
        if (lb * BS + qq < n) {
            float gv = gc[(size_t)(t0 + qq) * HH + h];
            o.x *= gv; o.y *= gv; o.z *= gv; o.w *= gv;
            *(float4*)(out + (size_t)(t0 + qq) * STRIDE + h * DD + dg * 4) = o;
        }
    }
    __syncthreads();

    // ---- phase 4: slc attention via MFMA, 2 software-pipelined steps ----
    unsigned int Msq[2];
    Msq[0] = Msk[l15];
    Msq[1] = Msk[16 + l15];

    f32x4 oacc[4][2];
    #pragma unroll
    for (int dt = 0; dt < 4; ++dt)
        #pragma unroll
        for (int qt = 0; qt < 2; ++qt)
            oacc[dt][qt] = (f32x4){0.f, 0.f, 0.f, 0.f};

#define PACK_K(KX)                                                                     \
    _Pragma("unroll")                                                                  \
    for (int cc = 0; cc < 4; ++cc) {                                                   \
        float4 x = KX[cc * 2], y = KX[cc * 2 + 1];                                     \
        uint4 uu;                                                                      \
        uu.x = pk2bf(x.x, x.y); uu.y = pk2bf(x.z, x.w);                                \
        uu.z = pk2bf(y.x, y.y); uu.w = pk2bf(y.z, y.w);                                \
        int c = khf * 4 + cc;                                                          \
        *(uint4*)&Ks[w][krow][(c ^ (krow & 7)) * 8] = uu;                              \
    }

#define COMPUTE_STEP(KB, TV)                                                           \
    {                                                                                  \
        const int kb = (KB);                                                           \
        bf16x8 a1[2][2], b1[2][2];                                                     \
        _Pragma("unroll")                                                              \
        for (int ds = 0; ds < 2; ++ds)                                                 \
            _Pragma("unroll")                                                          \
            for (int tt = 0; tt < 2; ++tt) {                                           \
                a1[tt][ds] = *(bf16x8*)&Ks[w][tt * 16 + l15][((g + ds * 4) ^ (l15 & 7)) * 8]; \
                b1[tt][ds] = *(bf16x8*)&Qs[tt * 16 + l15][((g + ds * 4) ^ (l15 & 7)) * 8];    \
            }                                                                          \
        f32x4 s[2][2];                                                                 \
        _Pragma("unroll")                                                              \
        for (int kt = 0; kt < 2; ++kt)                                                 \
            _Pragma("unroll")                                                          \
            for (int qt = 0; qt < 2; ++qt) {                                           \
                s[kt][qt] = (f32x4){0.f, 0.f, 0.f, 0.f};                               \
                s[kt][qt] = __builtin_amdgcn_mfma_f32_16x16x32_bf16(a1[kt][0], b1[qt][0], s[kt][qt], 0, 0, 0); \
                s[kt][qt] = __builtin_amdgcn_mfma_f32_16x16x32_bf16(a1[kt][1], b1[qt][1], s[kt][qt], 0, 0, 0); \
            }                                                                          \
        _Pragma("unroll")                                                              \
        for (int kt = 0; kt < 2; ++kt)                                                 \
            _Pragma("unroll")                                                          \
            for (int qt = 0; qt < 2; ++qt) {                                           \
                bool selbit = (Msq[qt] >> kb) & 1u;                                    \
                float pv[4];                                                           \
                _Pragma("unroll")                                                      \
                for (int r = 0; r < 4; ++r) {                                          \
                    int k_l = kt * 16 + g * 4 + r;                                     \
                    int q_l = qt * 16 + l15;                                           \
                    bool ok = selbit && (kb < lb || k_l <= q_l);                       \
                    pv[r] = ok ? silu_f(s[kt][qt][r]) : 0.f;                           \
                }                                                                      \
                Pw[w][qt * 16 + l15][kt * 8 + g * 2 + 0] = pk2bf(pv[0], pv[1]);        \
                Pw[w][qt * 16 + l15][kt * 8 + g * 2 + 1] = pk2bf(pv[2], pv[3]);        \
            }                                                                          \
        bf16x8 b2[2];                                                                  \
        b2[0] = *(bf16x8*)&Pw[w][l15][g * 4];                                          \
        b2[1] = *(bf16x8*)&Pw[w][16 + l15][g * 4];                                     \
        bf16x8 a2[4];                                                                  \
        _Pragma("unroll")                                                              \
        for (int dt = 0; dt < 4; ++dt) {                                               \
            union { unsigned int u[4]; bf16x8 v8; } cu;                                \
            cu.u[0] = pk2bf(TV[dt][0], TV[dt][1]);                                     \
            cu.u[1] = pk2bf(TV[dt][2], TV[dt][3]);                                     \
            cu.u[2] = pk2bf(TV[dt][4], TV[dt][5]);                                     \
            cu.u[3] = pk2bf(TV[dt][6], TV[dt][7]);                                     \
            a2[dt] = cu.v8;                                                            \
        }                                                                              \
        _Pragma("unroll")                                                              \
        for (int dt = 0; dt < 4; ++dt)                                                 \
            _Pragma("unroll")                                                          \
            for (int qt = 0; qt < 2; ++qt)                                             \
                oacc[dt][qt] = __builtin_amdgcn_mfma_f32_16x16x32_bf16(a2[dt], b2[qt], oacc[dt][qt], 0, 0, 0); \
    }

    float4 kxn[8];
    float  tvn[4][8];
    if (have0) {
        PACK_K(K0)
        // software pipeline: issue step-1 loads BEFORE step-0 compute
        if (have1) {
            const float4* kp = (const float4*)(k + (size_t)(off + (w + 8) * BS + krow) * STRIDE
                                               + h * DD + khf * 32);
            #pragma unroll
            for (int cc = 0; cc < 8; ++cc) kxn[cc] = kp[cc];
            const float* vg = v + (size_t)(off + (w + 8) * BS) * STRIDE + h * DD;
            #pragma unroll
            for (int dt = 0; dt < 4; ++dt)
                #pragma unroll
                for (int j = 0; j < 8; ++j)
                    tvn[dt][j] = vg[(size_t)(g * 8 + j) * STRIDE + dt * 16 + l15];
        }
        COMPUTE_STEP(w, tv0)
    }
    if (have1) {
        PACK_K(kxn)
        COMPUTE_STEP(w + 8, tvn)
    }
#undef PACK_K
#undef COMPUTE_STEP

    // ---- phase 5: two-step plane accumulation ----
    if (w < 4) {
        #pragma unroll
        for (int dt = 0; dt < 4; ++dt)
            #pragma unroll
            for (int qt = 0; qt < 2; ++qt)
                #pragma unroll
                for (int r = 0; r < 4; ++r)
                    Op[w][qt * 16 + l15][dt * 16 + g * 4 + r] = oacc[dt][qt][r];
    }
    __syncthreads();
    if (w >= 4) {
        #pragma unroll
        for (int dt = 0; dt < 4; ++dt)
            #pragma unroll
            for (int qt = 0; qt < 2; ++qt)
                #pragma unroll
                for (int r = 0; r < 4; ++r)
                    Op[w - 4][qt * 16 + l15][dt * 16 + g * 4 + r] += oacc[dt][qt][r];
    }
    __syncthreads();

    // ---- phase 6: combine planes, gate, store o_slc ----
    {
        int qq = tid >> 4, dg = tid & 15;
        if (lb * BS + qq < n) {
            float gv = gs[(size_t)(t0 + qq) * HH + h];
            float o[4];
            #pragma unroll
            for (int i = 0; i < 4; ++i) {
                int d = dg * 4 + i;
                o[i] = (Op[0][qq][d] + Op[1][qq][d] + Op[2][qq][d] + Op[3][qq][d]) * gv;
            }
            *(float4*)(out + (size_t)T * STRIDE + (size_t)(t0 + qq) * STRIDE + h * DD + dg * 4)
                = (float4){o[0], o[1], o[2], o[3]};
        }
    }
}

// ---------------------------------------------------------------------------
extern "C" void kernel_launch(void* const* d_in, const int* in_sizes, int n_in,
                              void* d_out, int out_size, void* d_ws, size_t ws_size,
                              hipStream_t stream) {
    const float* q    = (const float*)d_in[0];
    const float* k    = (const float*)d_in[1];
    const float* v    = (const float*)d_in[2];
    const float* gc   = (const float*)d_in[3];
    const float* gs   = (const float*)d_in[4];
    const int*   offs = (const int*)d_in[5];   // JAX x64-off: int32 on device

    int B = in_sizes[5] - 1;
    int T = out_size / (2 * STRIDE);
    int nbcap  = (T + BS - 1) / BS;
    int nqbcap = nbcap + B;                    // upper bound on query blocks

    nsa_all<<<dim3((unsigned)(nqbcap * HH)), dim3(512), 0, stream>>>(
        q, k, v, gc, gs, offs, B, T, (float*)d_out);
}

// Round 11
// 17.865 us; speedup vs baseline: 3.5181x; 1.0972x over previous
//
#include <hip/hip_runtime.h>
#include <math.h>

#define HH 4
#define DD 64
#define BS 32
#define SSEL 4
#define STRIDE (HH * DD)

typedef __attribute__((ext_vector_type(8))) short bf16x8;
typedef __attribute__((ext_vector_type(4))) float f32x4;

__device__ __forceinline__ float silu_f(float x) { return x / (1.0f + __expf(-x)); }

__device__ __forceinline__ unsigned short f2bf(float f) {
    unsigned int x = __float_as_uint(f);
    return (unsigned short)((x + 0x7FFFu + ((x >> 16) & 1u)) >> 16);   // RNE
}
__device__ __forceinline__ unsigned int pk2bf(float a, float b) {
    return (unsigned int)f2bf(a) | ((unsigned int)f2bf(b) << 16);
}

// ---------------------------------------------------------------------------
// Single fused kernel. One WG (8 waves / 512 threads) per (query-block, head).
// Low-pressure variant: no cross-phase prefetch registers, no Ks LDS staging,
// Pw/Op share one LDS region (phase-disjoint, extra barrier).
__global__ __launch_bounds__(512, 2) void nsa_all(
        const float* __restrict__ q, const float* __restrict__ k,
        const float* __restrict__ v, const float* __restrict__ gc,
        const float* __restrict__ gs, const int* __restrict__ offs,
        int B, int T, float* __restrict__ out) {
    __shared__ float Qf[32][68];                 // f32 scaled q
    __shared__ float Kc[16][68];                 // f32 block-mean K
    __shared__ float Vc[16][64];                 // f32 block-mean V
    __shared__ float Sc[32][17];                 // cmp scores
    __shared__ float Ps[32][17];                 // silu(scores)
    __shared__ unsigned char selb[32][16];
    __shared__ unsigned int  Msk[32];
    __shared__ unsigned short Qs[32][64];        // bf16, chunk-XOR swizzled
    __shared__ __align__(16) char UN[4 * 32 * 68 * 4];   // Pw (ph4) / Op (ph5/6)

    unsigned int (*Pw)[32][20] = (unsigned int (*)[32][20])UN;   // 8*32*20*4 = 20.5 KB
    float        (*Op)[32][68] = (float (*)[32][68])UN;          // 4*32*68*4 = 34.8 KB

    int qbh = blockIdx.x;
    int h   = qbh & (HH - 1);
    int qb  = qbh / HH;

    int b = -1, lb = 0, cum = 0, off = 0, n = 0;
    for (int i = 0; i < B; ++i) {
        int o0 = offs[i], o1 = offs[i + 1];
        int nbi = (o1 - o0 + BS - 1) / BS;
        if (qb < cum + nbi) { b = i; lb = qb - cum; off = o0; n = o1 - o0; break; }
        cum += nbi;
    }
    if (b < 0) return;
    int t0  = off + lb * BS;
    int nbl = lb + 1;                // <= 16 (seqlen <= 512)
    const float scale = 0.125f;
    int tid = threadIdx.x;
    int w = tid >> 6, lane = tid & 63;
    int l15 = lane & 15, g = lane >> 4;

    // ---- phase 0a: stage Q (f32 + bf16 swizzled) ----
    {
        int row = tid >> 4, dg = tid & 15;
        int trow = min(t0 + row, T - 1);
        float4 a = *(const float4*)(q + (size_t)trow * STRIDE + h * DD + dg * 4);
        a.x *= scale; a.y *= scale; a.z *= scale; a.w *= scale;
        *(float4*)&Qf[row][dg * 4] = a;
        uint2 uu = { pk2bf(a.x, a.y), pk2bf(a.z, a.w) };
        *(uint2*)&Qs[row][(((dg >> 1) ^ (row & 7)) * 8) + (dg & 1) * 4] = uu;
    }

    // ---- phase 0b: in-WG block means, one float4 column per thread ----
    if (tid < nbl * 32) {
        int j = tid >> 5, rest = tid & 31, kind = rest >> 4, d4 = rest & 15;
        const float* base = (kind ? v : k) + (size_t)(off + j * BS) * STRIDE + h * DD + d4 * 4;
        float4 acc = {0.f, 0.f, 0.f, 0.f};
        #pragma unroll
        for (int r = 0; r < BS; ++r) {
            float4 x = *(const float4*)(base + (size_t)r * STRIDE);
            acc.x += x.x; acc.y += x.y; acc.z += x.z; acc.w += x.w;
        }
        acc.x *= (1.f / BS); acc.y *= (1.f / BS); acc.z *= (1.f / BS); acc.w *= (1.f / BS);
        if (kind) *(float4*)&Vc[j][d4 * 4] = acc;
        else      *(float4*)&Kc[j][d4 * 4] = acc;
    }
    __syncthreads();

    // ---- phase 1: cmp scores fp32 (exact), one (q, blk) per thread ----
    {
        int qq = tid >> 4, j = tid & 15;
        if (j < nbl) {
            float s = 0.f;
            #pragma unroll
            for (int i = 0; i < 16; ++i) {
                float4 qv = *(float4*)&Qf[qq][i * 4];
                float4 kk = *(float4*)&Kc[j][i * 4];
                s += qv.x * kk.x + qv.y * kk.y + qv.z * kk.z + qv.w * kk.w;
            }
            Sc[qq][j] = s;
        }
    }
    __syncthreads();

    // ---- phase 2: rank -> selection bits + silu table ----
    {
        int qq = tid >> 4, j = tid & 15;
        if (j < nbl) {
            float sj = Sc[qq][j];
            int rank = 0;
            for (int i = 0; i < nbl; ++i) {
                float si = Sc[qq][i];
                rank += (si > sj) || (si == sj && i < j);
            }
            selb[qq][j] = (unsigned char)(rank < SSEL);
            Ps[qq][j]   = silu_f(sj);
        } else {
            selb[qq][j] = 0;
        }
    }
    __syncthreads();

    // ---- phase 3: masks + cmp PV + gc gate + store o_cmp ----
    if (tid < 32) {
        unsigned int m = 0;
        #pragma unroll
        for (int j = 0; j < 16; ++j) m |= ((unsigned int)selb[tid][j]) << j;
        Msk[tid] = m;
    }
    {
        int qq = tid >> 4, dg = tid & 15;
        float4 o = {0.f, 0.f, 0.f, 0.f};
        for (int blk = 0; blk < nbl; ++blk) {
            float p = Ps[qq][blk];
            float4 vv = *(float4*)&Vc[blk][dg * 4];
            o.x += p * vv.x; o.y += p * vv.y; o.z += p * vv.z; o.w += p * vv.w;
        }
        if (lb * BS + qq < n) {
            float gv = gc[(size_t)(t0 + qq) * HH + h];
            o.x *= gv; o.y *= gv; o.z *= gv; o.w *= gv;
            *(float4*)(out + (size_t)(t0 + qq) * STRIDE + h * DD + dg * 4) = o;
        }
    }
    __syncthreads();

    // ---- phase 4: slc attention via MFMA; loads at step head, low pressure ----
    unsigned int Msq[2];
    Msq[0] = Msk[l15];
    Msq[1] = Msk[16 + l15];

    f32x4 oacc[4][2];
    #pragma unroll
    for (int dt = 0; dt < 4; ++dt)
        #pragma unroll
        for (int qt = 0; qt < 2; ++qt)
            oacc[dt][qt] = (f32x4){0.f, 0.f, 0.f, 0.f};

    #pragma unroll 1
    for (int kb = w; kb <= lb; kb += 8) {
        const float* kbase = k + (size_t)(off + kb * BS) * STRIDE + h * DD;
        const float* vbase = v + (size_t)(off + kb * BS) * STRIDE + h * DD;

        // K fragments direct from global: a1[tt][ds] = K[tt*16+l15][ds*32+g*8 ..+7]
        float4 kf[2][2][2];
        #pragma unroll
        for (int tt = 0; tt < 2; ++tt)
            #pragma unroll
            for (int ds = 0; ds < 2; ++ds) {
                const float4* p = (const float4*)(kbase + (size_t)(tt * 16 + l15) * STRIDE
                                                  + ds * 32 + g * 8);
                kf[tt][ds][0] = p[0];
                kf[tt][ds][1] = p[1];
            }
        // V^T gather (transpose): tv[dt][j] = V[g*8+j][dt*16+l15]
        float tv[4][8];
        #pragma unroll
        for (int dt = 0; dt < 4; ++dt)
            #pragma unroll
            for (int j = 0; j < 8; ++j)
                tv[dt][j] = vbase[(size_t)(g * 8 + j) * STRIDE + dt * 16 + l15];

        bf16x8 a1[2][2];
        #pragma unroll
        for (int tt = 0; tt < 2; ++tt)
            #pragma unroll
            for (int ds = 0; ds < 2; ++ds) {
                union { unsigned int u[4]; bf16x8 v8; } cu;
                float4 x = kf[tt][ds][0], y = kf[tt][ds][1];
                cu.u[0] = pk2bf(x.x, x.y); cu.u[1] = pk2bf(x.z, x.w);
                cu.u[2] = pk2bf(y.x, y.y); cu.u[3] = pk2bf(y.z, y.w);
                a1[tt][ds] = cu.v8;
            }
        bf16x8 b1[2][2];
        #pragma unroll
        for (int ds = 0; ds < 2; ++ds)
            #pragma unroll
            for (int tt = 0; tt < 2; ++tt)
                b1[tt][ds] = *(bf16x8*)&Qs[tt * 16 + l15][((g + ds * 4) ^ (l15 & 7)) * 8];

        f32x4 s[2][2];
        #pragma unroll
        for (int kt = 0; kt < 2; ++kt)
            #pragma unroll
            for (int qt = 0; qt < 2; ++qt) {
                s[kt][qt] = (f32x4){0.f, 0.f, 0.f, 0.f};
                s[kt][qt] = __builtin_amdgcn_mfma_f32_16x16x32_bf16(a1[kt][0], b1[qt][0], s[kt][qt], 0, 0, 0);
                s[kt][qt] = __builtin_amdgcn_mfma_f32_16x16x32_bf16(a1[kt][1], b1[qt][1], s[kt][qt], 0, 0, 0);
            }

        // mask + silu + pack P (bf16) via wave-private LDS (layout shuffle)
        #pragma unroll
        for (int kt = 0; kt < 2; ++kt)
            #pragma unroll
            for (int qt = 0; qt < 2; ++qt) {
                bool selbit = (Msq[qt] >> kb) & 1u;
                float pv[4];
                #pragma unroll
                for (int r = 0; r < 4; ++r) {
                    int k_l = kt * 16 + g * 4 + r;
                    int q_l = qt * 16 + l15;
                    bool ok = selbit && (kb < lb || k_l <= q_l);
                    pv[r] = ok ? silu_f(s[kt][qt][r]) : 0.f;
                }
                Pw[w][qt * 16 + l15][kt * 8 + g * 2 + 0] = pk2bf(pv[0], pv[1]);
                Pw[w][qt * 16 + l15][kt * 8 + g * 2 + 1] = pk2bf(pv[2], pv[3]);
            }
        bf16x8 b2[2];
        b2[0] = *(bf16x8*)&Pw[w][l15][g * 4];
        b2[1] = *(bf16x8*)&Pw[w][16 + l15][g * 4];

        bf16x8 a2[4];
        #pragma unroll
        for (int dt = 0; dt < 4; ++dt) {
            union { unsigned int u[4]; bf16x8 v8; } cu;
            cu.u[0] = pk2bf(tv[dt][0], tv[dt][1]);
            cu.u[1] = pk2bf(tv[dt][2], tv[dt][3]);
            cu.u[2] = pk2bf(tv[dt][4], tv[dt][5]);
            cu.u[3] = pk2bf(tv[dt][6], tv[dt][7]);
            a2[dt] = cu.v8;
        }

        #pragma unroll
        for (int dt = 0; dt < 4; ++dt)
            #pragma unroll
            for (int qt = 0; qt < 2; ++qt)
                oacc[dt][qt] = __builtin_amdgcn_mfma_f32_16x16x32_bf16(a2[dt], b2[qt], oacc[dt][qt], 0, 0, 0);
    }
    __syncthreads();   // all waves done with Pw before Op overlays it

    // ---- phase 5: two-step plane accumulation ----
    if (w < 4) {
        #pragma unroll
        for (int dt = 0; dt < 4; ++dt)
            #pragma unroll
            for (int qt = 0; qt < 2; ++qt)
                #pragma unroll
                for (int r = 0; r < 4; ++r)
                    Op[w][qt * 16 + l15][dt * 16 + g * 4 + r] = oacc[dt][qt][r];
    }
    __syncthreads();
    if (w >= 4) {
        #pragma unroll
        for (int dt = 0; dt < 4; ++dt)
            #pragma unroll
            for (int qt = 0; qt < 2; ++qt)
                #pragma unroll
                for (int r = 0; r < 4; ++r)
                    Op[w - 4][qt * 16 + l15][dt * 16 + g * 4 + r] += oacc[dt][qt][r];
    }
    __syncthreads();

    // ---- phase 6: combine planes, gate, store o_slc ----
    {
        int qq = tid >> 4, dg = tid & 15;
        if (lb * BS + qq < n) {
            float gv = gs[(size_t)(t0 + qq) * HH + h];
            float o[4];
            #pragma unroll
            for (int i = 0; i < 4; ++i) {
                int d = dg * 4 + i;
                o[i] = (Op[0][qq][d] + Op[1][qq][d] + Op[2][qq][d] + Op[3][qq][d]) * gv;
            }
            *(float4*)(out + (size_t)T * STRIDE + (size_t)(t0 + qq) * STRIDE + h * DD + dg * 4)
                = (float4){o[0], o[1], o[2], o[3]};
        }
    }
}

// ---------------------------------------------------------------------------
extern "C" void kernel_launch(void* const* d_in, const int* in_sizes, int n_in,
                              void* d_out, int out_size, void* d_ws, size_t ws_size,
                              hipStream_t stream) {
    const float* q    = (const float*)d_in[0];
    const float* k    = (const float*)d_in[1];
    const float* v    = (const float*)d_in[2];
    const float* gc   = (const float*)d_in[3];
    const float* gs   = (const float*)d_in[4];
    const int*   offs = (const int*)d_in[5];   // JAX x64-off: int32 on device

    int B = in_sizes[5] - 1;
    int T = out_size / (2 * STRIDE);
    int nbcap  = (T + BS - 1) / BS;
    int nqbcap = nbcap + B;                    // upper bound on query blocks

    nsa_all<<<dim3((unsigned)(nqbcap * HH)), dim3(512), 0, stream>>>(
        q, k, v, gc, gs, offs, B, T, (float*)d_out);
}